// Round 4
// baseline (1027.886 us; speedup 1.0000x reference)
//
#include <hip/hip_runtime.h>

#define FDIM 64
#define EPS 1e-5f
#define NBUCK 1024     // coarse buckets = high bits of 17-bit id
#define LOWB 7
#define LOWMASK 127

// ---------------- coarse histograms (LDS-privatized) of src>>7 and dst>>7 ----------------
__global__ void k_chist(const int* __restrict__ src, const int* __restrict__ dst,
                        int* __restrict__ coarseS, int* __restrict__ coarseD, int E) {
    __shared__ int hs[NBUCK], hd[NBUCK];
    int tid = threadIdx.x;
    for (int k = tid; k < NBUCK; k += 256) { hs[k] = 0; hd[k] = 0; }
    __syncthreads();
    int stride = gridDim.x * blockDim.x;
    for (int i = blockIdx.x * blockDim.x + tid; i < E; i += stride) {
        atomicAdd(&hs[src[i] >> LOWB], 1);
        atomicAdd(&hd[dst[i] >> LOWB], 1);
    }
    __syncthreads();
    for (int k = tid; k < NBUCK; k += 256) {
        if (hs[k]) atomicAdd(&coarseS[k], hs[k]);
        if (hd[k]) atomicAdd(&coarseD[k], hd[k]);
    }
}

// ---------------- exclusive scan of both coarse histograms ----------------
__global__ void k_cscan(const int* __restrict__ coarseS, const int* __restrict__ coarseD,
                        int* __restrict__ baseS, int* __restrict__ cursorS,
                        int* __restrict__ baseD, int* __restrict__ cursorD) {
    __shared__ int s[NBUCK];
    int tid = threadIdx.x;
    s[tid] = coarseS[tid];
    __syncthreads();
    for (int off = 1; off < NBUCK; off <<= 1) {
        int t = (tid >= off) ? s[tid - off] : 0;
        __syncthreads();
        s[tid] += t;
        __syncthreads();
    }
    int exclS = (tid > 0) ? s[tid - 1] : 0;
    baseS[tid] = exclS; cursorS[tid] = exclS;
    if (tid == NBUCK - 1) baseS[NBUCK] = s[NBUCK - 1];
    __syncthreads();
    s[tid] = coarseD[tid];
    __syncthreads();
    for (int off = 1; off < NBUCK; off <<= 1) {
        int t = (tid >= off) ? s[tid - off] : 0;
        __syncthreads();
        s[tid] += t;
        __syncthreads();
    }
    int exclD = (tid > 0) ? s[tid - 1] : 0;
    baseD[tid] = exclD; cursorD[tid] = exclD;
    if (tid == NBUCK - 1) baseD[NBUCK] = s[NBUCK - 1];
}

// ---------------- bucket edges by coarse id (1024 hot cursors, line-dense writes) ----------------
__global__ void k_bucket(const int* __restrict__ src, const int* __restrict__ dst,
                         int* __restrict__ cursorS, int* __restrict__ cursorD,
                         unsigned char* __restrict__ tmpS, int* __restrict__ tmpD, int E) {
    int i4 = (blockIdx.x * blockDim.x + threadIdx.x) * 4;
    if (i4 + 3 < E) {
        int4 s = *(const int4*)(src + i4);
        int4 d = *(const int4*)(dst + i4);
        int p;
        p = atomicAdd(&cursorS[s.x >> LOWB], 1); tmpS[p] = (unsigned char)(s.x & LOWMASK);
        p = atomicAdd(&cursorS[s.y >> LOWB], 1); tmpS[p] = (unsigned char)(s.y & LOWMASK);
        p = atomicAdd(&cursorS[s.z >> LOWB], 1); tmpS[p] = (unsigned char)(s.z & LOWMASK);
        p = atomicAdd(&cursorS[s.w >> LOWB], 1); tmpS[p] = (unsigned char)(s.w & LOWMASK);
        p = atomicAdd(&cursorD[d.x >> LOWB], 1); tmpD[p] = (s.x << LOWB) | (d.x & LOWMASK);
        p = atomicAdd(&cursorD[d.y >> LOWB], 1); tmpD[p] = (s.y << LOWB) | (d.y & LOWMASK);
        p = atomicAdd(&cursorD[d.z >> LOWB], 1); tmpD[p] = (s.z << LOWB) | (d.z & LOWMASK);
        p = atomicAdd(&cursorD[d.w >> LOWB], 1); tmpD[p] = (s.w << LOWB) | (d.w & LOWMASK);
    } else {
        for (int i = i4; i < E; ++i) {
            int sv = src[i], dv = dst[i];
            int p = atomicAdd(&cursorS[sv >> LOWB], 1);
            tmpS[p] = (unsigned char)(sv & LOWMASK);
            p = atomicAdd(&cursorD[dv >> LOWB], 1);
            tmpD[p] = (sv << LOWB) | (dv & LOWMASK);
        }
    }
}

// ---------------- per-bucket: fine hist + scan -> rowptr, LDS-cursor scatter -> csr_src ----------------
__global__ void k_finebucket(const int* __restrict__ tmp, const int* __restrict__ base,
                             int* __restrict__ csr_src, int* __restrict__ rowptr, int N) {
    __shared__ int hist[128];
    __shared__ int scanv[128];
    int b = blockIdx.x;
    int tid = threadIdx.x;
    int s0 = base[b];
    int s1 = base[b + 1];
    if (tid < 128) hist[tid] = 0;
    __syncthreads();
    for (int i = s0 + tid; i < s1; i += 256)
        atomicAdd(&hist[tmp[i] & LOWMASK], 1);
    __syncthreads();
    int mine = (tid < 128) ? hist[tid] : 0;
    if (tid < 128) scanv[tid] = mine;
    __syncthreads();
    for (int off = 1; off < 128; off <<= 1) {
        int t = (tid < 128 && tid >= off) ? scanv[tid - off] : 0;
        __syncthreads();
        if (tid < 128) scanv[tid] += t;
        __syncthreads();
    }
    if (tid < 128) {
        int excl = scanv[tid] - mine;       // exclusive scan
        int d = (b << LOWB) + tid;
        if (d <= N) rowptr[d] = s0 + excl;  // covers rowptr[N]=E too
        hist[tid] = excl;                   // LDS cursors
    }
    __syncthreads();
    for (int i = s0 + tid; i < s1; i += 256) {
        int p = tmp[i];
        int pos = atomicAdd(&hist[p & LOWMASK], 1);
        csr_src[s0 + pos] = p >> LOWB;
    }
}

// ---------------- per-bucket histogram only -> degO ----------------
__global__ void k_finehist(const unsigned char* __restrict__ tmp, const int* __restrict__ base,
                           int* __restrict__ degO, int N) {
    __shared__ int hist[128];
    int b = blockIdx.x;
    int tid = threadIdx.x;
    int s0 = base[b];
    int s1 = base[b + 1];
    if (tid < 128) hist[tid] = 0;
    __syncthreads();
    for (int i = s0 + tid; i < s1; i += 256)
        atomicAdd(&hist[tmp[i]], 1);
    __syncthreads();
    if (tid < 128) {
        int d = (b << LOWB) + tid;
        if (d < N) degO[d] = hist[tid];
    }
}

// ---------------- bufA = x * rsqrt(max(degO,1)) ----------------
__global__ void k_scalex(const float4* __restrict__ x, const int* __restrict__ degO,
                         float4* __restrict__ out, int n4) {
    int i = blockIdx.x * blockDim.x + threadIdx.x;
    if (i < n4) {
        int n = i >> 4;
        float rs = rsqrtf((float)max(degO[n], 1));
        float4 v = x[i];
        v.x *= rs; v.y *= rs; v.z *= rs; v.w *= rs;
        out[i] = v;
    }
}

// ---------------- CSR SpMM: one wave per dst node, lane = feature ----------------
__global__ void k_spmm_csr(const float* __restrict__ hin, const int* __restrict__ rowptr,
                           const int* __restrict__ csr_src, float* __restrict__ out, int N) {
    int wave = (blockIdx.x * blockDim.x + threadIdx.x) >> 6;
    int lane = threadIdx.x & 63;
    if (wave >= N) return;
    int start = rowptr[wave];
    int end   = rowptr[wave + 1];
    float a0 = 0.f, a1 = 0.f, a2 = 0.f, a3 = 0.f;
    int e = start;
    for (; e + 4 <= end; e += 4) {
        int s0 = csr_src[e];
        int s1 = csr_src[e + 1];
        int s2 = csr_src[e + 2];
        int s3 = csr_src[e + 3];
        a0 += hin[(size_t)s0 * FDIM + lane];
        a1 += hin[(size_t)s1 * FDIM + lane];
        a2 += hin[(size_t)s2 * FDIM + lane];
        a3 += hin[(size_t)s3 * FDIM + lane];
    }
    for (; e < end; ++e)
        a0 += hin[(size_t)csr_src[e] * FDIM + lane];
    float rs = rsqrtf(fmaxf((float)(end - start), 1.0f));
    out[(size_t)wave * FDIM + lane] = ((a0 + a1) + (a2 + a3)) * rs;
}

// ---------------- GEMM (N,64)x(64,64) + bias + BN stats ----------------
__global__ void k_gemm_stats(const float* __restrict__ m, const float* __restrict__ W,
                             const float* __restrict__ b, float* __restrict__ out,
                             float* __restrict__ ssum, float* __restrict__ ssq, int N) {
    __shared__ float Ws[FDIM * FDIM];
    __shared__ float ms[4 * FDIM];
    __shared__ float red[256];
    int tid = threadIdx.x;
    for (int i = tid; i < FDIM * FDIM; i += 256) Ws[i] = W[i];
    int j  = tid & 63;
    int nl = tid >> 6;
    float bj = b[j];
    float lsum = 0.f, lsq = 0.f;
    int nchunks = (N + 3) >> 2;
    for (int chunk = blockIdx.x; chunk < nchunks; chunk += gridDim.x) {
        int n = (chunk << 2) + nl;
        __syncthreads();
        ms[tid] = (n < N) ? m[(size_t)n * FDIM + j] : 0.f;
        __syncthreads();
        if (n < N) {
            float acc = 0.f;
#pragma unroll
            for (int k = 0; k < FDIM; ++k)
                acc += ms[nl * FDIM + k] * Ws[k * FDIM + j];
            float h = acc + bj;
            out[(size_t)n * FDIM + j] = h;
            lsum += h;
            lsq += h * h;
        }
    }
    __syncthreads();
    red[tid] = lsum;
    __syncthreads();
    if (nl == 0) atomicAdd(&ssum[j], red[j] + red[64 + j] + red[128 + j] + red[192 + j]);
    __syncthreads();
    red[tid] = lsq;
    __syncthreads();
    if (nl == 0) atomicAdd(&ssq[j], red[j] + red[64 + j] + red[128 + j] + red[192 + j]);
}

// ---------------- finalize BN params ----------------
__global__ void k_finalize(const float* __restrict__ ssum, const float* __restrict__ ssq,
                           const float* __restrict__ g, float* __restrict__ mu,
                           float* __restrict__ coef, int N) {
    int j = threadIdx.x;
    float m = ssum[j] / (float)N;
    float v = ssq[j] / (float)N - m * m;
    mu[j] = m;
    coef[j] = rsqrtf(v + EPS) * g[j];
}

// ---------------- out = relu((h-mu)*coef+be) * rsqrt(max(degO,1)) ----------------
__global__ void k_bnrelu_scale(const float4* __restrict__ h, const float* __restrict__ mu,
                               const float* __restrict__ coef, const float* __restrict__ be,
                               const int* __restrict__ degO, float4* __restrict__ out, int n4) {
    int i = blockIdx.x * blockDim.x + threadIdx.x;
    if (i < n4) {
        int n = i >> 4;
        int j4 = (i & 15) << 2;
        float rs = rsqrtf((float)max(degO[n], 1));
        float4 v = h[i];
        v.x = fmaxf((v.x - mu[j4 + 0]) * coef[j4 + 0] + be[j4 + 0], 0.f) * rs;
        v.y = fmaxf((v.y - mu[j4 + 1]) * coef[j4 + 1] + be[j4 + 1], 0.f) * rs;
        v.z = fmaxf((v.z - mu[j4 + 2]) * coef[j4 + 2] + be[j4 + 2], 0.f) * rs;
        v.w = fmaxf((v.w - mu[j4 + 3]) * coef[j4 + 3] + be[j4 + 3], 0.f) * rs;
        out[i] = v;
    }
}

// ---------------- relu(bn(h)) channel-sum over nodes ----------------
__global__ void k_bnrelu_mean(const float* __restrict__ h, const float* __restrict__ mu,
                              const float* __restrict__ coef, const float* __restrict__ be,
                              float* __restrict__ hsum, int N) {
    __shared__ float red[256];
    int tid = threadIdx.x;
    int j  = tid & 63;
    int nl = tid >> 6;
    float muj = mu[j], cj = coef[j], bj = be[j];
    float ls = 0.f;
    int nchunks = (N + 3) >> 2;
    for (int chunk = blockIdx.x; chunk < nchunks; chunk += gridDim.x) {
        int n = (chunk << 2) + nl;
        if (n < N) {
            float v = fmaxf((h[(size_t)n * FDIM + j] - muj) * cj + bj, 0.f);
            ls += v;
        }
    }
    red[tid] = ls;
    __syncthreads();
    if (nl == 0) atomicAdd(&hsum[j], red[j] + red[64 + j] + red[128 + j] + red[192 + j]);
}

// ---------------- classifier ----------------
__global__ void k_final(const float* __restrict__ hsum, const float* __restrict__ Wc,
                        const float* __restrict__ bc, float* __restrict__ out, int N) {
    __shared__ float red[128];
    int j = threadIdx.x;
    float hg = hsum[j] / (float)N;
    red[j]      = hg * Wc[j * 2 + 0];
    red[64 + j] = hg * Wc[j * 2 + 1];
    __syncthreads();
    if (j == 0) {
        float a = 0.f, b = 0.f;
        for (int k = 0; k < 64; ++k) { a += red[k]; b += red[64 + k]; }
        out[0] = a + bc[0];
        out[1] = b + bc[1];
    }
}

extern "C" void kernel_launch(void* const* d_in, const int* in_sizes, int n_in,
                              void* d_out, int out_size, void* d_ws, size_t ws_size,
                              hipStream_t stream) {
    const float* x   = (const float*)d_in[0];
    const int*   src = (const int*)d_in[1];
    const int*   dst = (const int*)d_in[2];
    const float* W1  = (const float*)d_in[3];
    const float* b1  = (const float*)d_in[4];
    const float* g1  = (const float*)d_in[5];
    const float* be1 = (const float*)d_in[6];
    const float* W2  = (const float*)d_in[7];
    const float* b2  = (const float*)d_in[8];
    const float* g2  = (const float*)d_in[9];
    const float* be2 = (const float*)d_in[10];
    const float* Wc  = (const float*)d_in[11];
    const float* bc  = (const float*)d_in[12];
    float* out = (float*)d_out;

    const int N = in_sizes[0] / FDIM;   // 100000
    const int E = in_sizes[1];          // 1600000

    // ---- workspace layout ----
    char* w = (char*)d_ws;
    float* bufA    = (float*)w;                                   // N*64 f
    float* bufB    = bufA + (size_t)N * FDIM;                     // N*64 f
    int*   csr_src = (int*)(bufB + (size_t)N * FDIM);             // E int
    int*   degO    = csr_src + E;                                 // N int
    int*   rowptr  = degO + N;                                    // N+2 int
    int*   coarseS = rowptr + N + 2;                              // 1024 } memset
    int*   coarseD = coarseS + NBUCK;                             // 1024 } memset
    float* stats   = (float*)(coarseD + NBUCK);                   // 1024 } memset
    int*   baseS   = (int*)(stats + 1024);                        // 1025
    int*   cursorS = baseS + NBUCK + 1;                           // 1024
    int*   baseD   = cursorS + NBUCK;                             // 1025
    int*   cursorD = baseD + NBUCK + 1;                           // 1024

    // tmp bucket payloads alias the big buffers (dead before bufA/bufB first writes)
    unsigned char* tmpS = (unsigned char*)bufA;                   // E bytes
    int*           tmpD = (int*)bufB;                             // E int

    float* sum1  = stats + 0;
    float* sq1   = stats + 64;
    float* mu1   = stats + 128;
    float* coef1 = stats + 192;
    float* sum2  = stats + 256;
    float* sq2   = stats + 320;
    float* mu2   = stats + 384;
    float* coef2 = stats + 448;
    float* hsum  = stats + 512;

    const int n4 = N * (FDIM / 4);
    const int spmm_blocks = (N * (FDIM / 4) + 63) / 64;   // N waves, 4 waves/block
    const int nbuck_active = (N + LOWMASK) >> LOWB;       // 782 for N=100000
    const int e4blocks = ((E + 3) / 4 + 255) / 256;

    // zero coarse hists + stats (contiguous: 2*1024 ints + 1024 floats)
    hipMemsetAsync(coarseS, 0, (size_t)(3 * 1024) * 4, stream);

    k_chist<<<256, 256, 0, stream>>>(src, dst, coarseS, coarseD, E);
    k_cscan<<<1, NBUCK, 0, stream>>>(coarseS, coarseD, baseS, cursorS, baseD, cursorD);
    k_bucket<<<e4blocks, 256, 0, stream>>>(src, dst, cursorS, cursorD, tmpS, tmpD, E);
    k_finebucket<<<nbuck_active, 256, 0, stream>>>(tmpD, baseD, csr_src, rowptr, N);
    k_finehist<<<nbuck_active, 256, 0, stream>>>(tmpS, baseS, degO, N);

    k_scalex<<<(n4 + 255) / 256, 256, 0, stream>>>((const float4*)x, degO, (float4*)bufA, n4);
    k_spmm_csr<<<spmm_blocks, 256, 0, stream>>>(bufA, rowptr, csr_src, bufB, N);
    k_gemm_stats<<<1024, 256, 0, stream>>>(bufB, W1, b1, bufA, sum1, sq1, N);
    k_finalize<<<1, 64, 0, stream>>>(sum1, sq1, g1, mu1, coef1, N);
    k_bnrelu_scale<<<(n4 + 255) / 256, 256, 0, stream>>>((const float4*)bufA, mu1, coef1, be1,
                                                         degO, (float4*)bufB, n4);
    k_spmm_csr<<<spmm_blocks, 256, 0, stream>>>(bufB, rowptr, csr_src, bufA, N);
    k_gemm_stats<<<1024, 256, 0, stream>>>(bufA, W2, b2, bufB, sum2, sq2, N);
    k_finalize<<<1, 64, 0, stream>>>(sum2, sq2, g2, mu2, coef2, N);
    k_bnrelu_mean<<<1024, 256, 0, stream>>>(bufB, mu2, coef2, be2, hsum, N);
    k_final<<<1, 64, 0, stream>>>(hsum, Wc, bc, out, N);
}

// Round 5
// 510.582 us; speedup vs baseline: 2.0132x; 2.0132x over previous
//
#include <hip/hip_runtime.h>

#define FDIM 64
#define EPS 1e-5f
#define NBUCK 1024     // coarse buckets = high bits of 17-bit id
#define LOWB 7
#define LOWMASK 127
#define RB 128         // radix blocks
#define RT 1024        // radix threads per block

// ---------------- per-block coarse histograms of src>>7 and dst>>7 ----------------
__global__ void k_hist(const int* __restrict__ src, const int* __restrict__ dst,
                       int* __restrict__ histS, int* __restrict__ histD, int E, int chunk) {
    __shared__ int hs[NBUCK], hd[NBUCK];
    int tid = threadIdx.x;            // RT == NBUCK == 1024
    hs[tid] = 0; hd[tid] = 0;
    __syncthreads();
    int b = blockIdx.x;
    int beg = b * chunk;
    int end = min(E, beg + chunk);
    int i = beg + tid * 4;
    for (; i + 3 < end; i += RT * 4) {
        int4 s = *(const int4*)(src + i);
        int4 d = *(const int4*)(dst + i);
        atomicAdd(&hs[s.x >> LOWB], 1); atomicAdd(&hd[d.x >> LOWB], 1);
        atomicAdd(&hs[s.y >> LOWB], 1); atomicAdd(&hd[d.y >> LOWB], 1);
        atomicAdd(&hs[s.z >> LOWB], 1); atomicAdd(&hd[d.z >> LOWB], 1);
        atomicAdd(&hs[s.w >> LOWB], 1); atomicAdd(&hd[d.w >> LOWB], 1);
    }
    if (i < end) {
        for (int j = i; j < end && j < i + 4; ++j) {
            atomicAdd(&hs[src[j] >> LOWB], 1);
            atomicAdd(&hd[dst[j] >> LOWB], 1);
        }
    }
    __syncthreads();
    histS[b * NBUCK + tid] = hs[tid];
    histD[b * NBUCK + tid] = hd[tid];
}

// ---------------- scan the [RB][NBUCK] matrix -> per-block offsets + bucket bases ----------------
// gridDim.x == 2: block 0 handles (histS, baseS), block 1 handles (histD, baseD).
__global__ void k_scan(int* __restrict__ histS, int* __restrict__ baseS,
                       int* __restrict__ histD, int* __restrict__ baseD, int B) {
    int* hist = (blockIdx.x == 0) ? histS : histD;
    int* base = (blockIdx.x == 0) ? baseS : baseD;
    __shared__ int s[NBUCK];
    int k = threadIdx.x;
    int run = 0;
    for (int b = 0; b < B; ++b) {
        int t = hist[b * NBUCK + k];
        hist[b * NBUCK + k] = run;
        run += t;
    }
    s[k] = run;
    __syncthreads();
    for (int off = 1; off < NBUCK; off <<= 1) {
        int t = (k >= off) ? s[k - off] : 0;
        __syncthreads();
        s[k] += t;
        __syncthreads();
    }
    int excl = (k > 0) ? s[k - 1] : 0;
    base[k] = excl;
    if (k == NBUCK - 1) base[NBUCK] = s[NBUCK - 1];
    for (int b = 0; b < B; ++b)
        hist[b * NBUCK + k] += excl;
}

// ---------------- coarse partition: LDS cursors per block, no global atomics ----------------
__global__ void k_bucket(const int* __restrict__ src, const int* __restrict__ dst,
                         const int* __restrict__ histS, const int* __restrict__ histD,
                         unsigned char* __restrict__ tmpS, int* __restrict__ tmpD,
                         int E, int chunk) {
    __shared__ int curS[NBUCK], curD[NBUCK];
    int tid = threadIdx.x;
    int b = blockIdx.x;
    curS[tid] = histS[b * NBUCK + tid];
    curD[tid] = histD[b * NBUCK + tid];
    __syncthreads();
    int beg = b * chunk;
    int end = min(E, beg + chunk);
    int i = beg + tid * 4;
    for (; i + 3 < end; i += RT * 4) {
        int4 s = *(const int4*)(src + i);
        int4 d = *(const int4*)(dst + i);
        int p;
        p = atomicAdd(&curS[s.x >> LOWB], 1); tmpS[p] = (unsigned char)(s.x & LOWMASK);
        p = atomicAdd(&curS[s.y >> LOWB], 1); tmpS[p] = (unsigned char)(s.y & LOWMASK);
        p = atomicAdd(&curS[s.z >> LOWB], 1); tmpS[p] = (unsigned char)(s.z & LOWMASK);
        p = atomicAdd(&curS[s.w >> LOWB], 1); tmpS[p] = (unsigned char)(s.w & LOWMASK);
        p = atomicAdd(&curD[d.x >> LOWB], 1); tmpD[p] = (s.x << LOWB) | (d.x & LOWMASK);
        p = atomicAdd(&curD[d.y >> LOWB], 1); tmpD[p] = (s.y << LOWB) | (d.y & LOWMASK);
        p = atomicAdd(&curD[d.z >> LOWB], 1); tmpD[p] = (s.z << LOWB) | (d.z & LOWMASK);
        p = atomicAdd(&curD[d.w >> LOWB], 1); tmpD[p] = (s.w << LOWB) | (d.w & LOWMASK);
    }
    if (i < end) {
        for (int j = i; j < end && j < i + 4; ++j) {
            int sv = src[j], dv = dst[j];
            int p = atomicAdd(&curS[sv >> LOWB], 1);
            tmpS[p] = (unsigned char)(sv & LOWMASK);
            p = atomicAdd(&curD[dv >> LOWB], 1);
            tmpD[p] = (sv << LOWB) | (dv & LOWMASK);
        }
    }
}

// ---------------- per-bucket: fine hist + scan -> rowptr, LDS-cursor scatter -> csr_src ----------------
__global__ void k_finebucket(const int* __restrict__ tmp, const int* __restrict__ base,
                             int* __restrict__ csr_src, int* __restrict__ rowptr, int N) {
    __shared__ int hist[128];
    __shared__ int scanv[128];
    int b = blockIdx.x;
    int tid = threadIdx.x;
    int s0 = base[b];
    int s1 = base[b + 1];
    if (tid < 128) hist[tid] = 0;
    __syncthreads();
    for (int i = s0 + tid; i < s1; i += 256)
        atomicAdd(&hist[tmp[i] & LOWMASK], 1);
    __syncthreads();
    int mine = (tid < 128) ? hist[tid] : 0;
    if (tid < 128) scanv[tid] = mine;
    __syncthreads();
    for (int off = 1; off < 128; off <<= 1) {
        int t = (tid < 128 && tid >= off) ? scanv[tid - off] : 0;
        __syncthreads();
        if (tid < 128) scanv[tid] += t;
        __syncthreads();
    }
    if (tid < 128) {
        int excl = scanv[tid] - mine;       // exclusive scan
        int d = (b << LOWB) + tid;
        if (d <= N) rowptr[d] = s0 + excl;  // covers rowptr[N]=E too
        hist[tid] = excl;                   // LDS cursors
    }
    __syncthreads();
    for (int i = s0 + tid; i < s1; i += 256) {
        int p = tmp[i];
        int pos = atomicAdd(&hist[p & LOWMASK], 1);
        csr_src[s0 + pos] = p >> LOWB;
    }
}

// ---------------- per-bucket histogram only -> degO ----------------
__global__ void k_finehist(const unsigned char* __restrict__ tmp, const int* __restrict__ base,
                           int* __restrict__ degO, int N) {
    __shared__ int hist[128];
    int b = blockIdx.x;
    int tid = threadIdx.x;
    int s0 = base[b];
    int s1 = base[b + 1];
    if (tid < 128) hist[tid] = 0;
    __syncthreads();
    for (int i = s0 + tid; i < s1; i += 256)
        atomicAdd(&hist[tmp[i]], 1);
    __syncthreads();
    if (tid < 128) {
        int d = (b << LOWB) + tid;
        if (d < N) degO[d] = hist[tid];
    }
}

// ---------------- bufA = x * rsqrt(max(degO,1)) ----------------
__global__ void k_scalex(const float4* __restrict__ x, const int* __restrict__ degO,
                         float4* __restrict__ out, int n4) {
    int i = blockIdx.x * blockDim.x + threadIdx.x;
    if (i < n4) {
        int n = i >> 4;
        float rs = rsqrtf((float)max(degO[n], 1));
        float4 v = x[i];
        v.x *= rs; v.y *= rs; v.z *= rs; v.w *= rs;
        out[i] = v;
    }
}

// ---------------- CSR SpMM: one wave per dst node, lane = feature ----------------
__global__ void k_spmm_csr(const float* __restrict__ hin, const int* __restrict__ rowptr,
                           const int* __restrict__ csr_src, float* __restrict__ out, int N) {
    int wave = (blockIdx.x * blockDim.x + threadIdx.x) >> 6;
    int lane = threadIdx.x & 63;
    if (wave >= N) return;
    int start = rowptr[wave];
    int end   = rowptr[wave + 1];
    float a0 = 0.f, a1 = 0.f, a2 = 0.f, a3 = 0.f;
    int e = start;
    for (; e + 4 <= end; e += 4) {
        int s0 = csr_src[e];
        int s1 = csr_src[e + 1];
        int s2 = csr_src[e + 2];
        int s3 = csr_src[e + 3];
        a0 += hin[(size_t)s0 * FDIM + lane];
        a1 += hin[(size_t)s1 * FDIM + lane];
        a2 += hin[(size_t)s2 * FDIM + lane];
        a3 += hin[(size_t)s3 * FDIM + lane];
    }
    for (; e < end; ++e)
        a0 += hin[(size_t)csr_src[e] * FDIM + lane];
    float rs = rsqrtf(fmaxf((float)(end - start), 1.0f));
    out[(size_t)wave * FDIM + lane] = ((a0 + a1) + (a2 + a3)) * rs;
}

// ---------------- GEMM (N,64)x(64,64) + bias + BN stats ----------------
__global__ void k_gemm_stats(const float* __restrict__ m, const float* __restrict__ W,
                             const float* __restrict__ b, float* __restrict__ out,
                             float* __restrict__ ssum, float* __restrict__ ssq, int N) {
    __shared__ float Ws[FDIM * FDIM];
    __shared__ float ms[4 * FDIM];
    __shared__ float red[256];
    int tid = threadIdx.x;
    for (int i = tid; i < FDIM * FDIM; i += 256) Ws[i] = W[i];
    int j  = tid & 63;
    int nl = tid >> 6;
    float bj = b[j];
    float lsum = 0.f, lsq = 0.f;
    int nchunks = (N + 3) >> 2;
    for (int chunk = blockIdx.x; chunk < nchunks; chunk += gridDim.x) {
        int n = (chunk << 2) + nl;
        __syncthreads();
        ms[tid] = (n < N) ? m[(size_t)n * FDIM + j] : 0.f;
        __syncthreads();
        if (n < N) {
            float acc = 0.f;
#pragma unroll
            for (int k = 0; k < FDIM; ++k)
                acc += ms[nl * FDIM + k] * Ws[k * FDIM + j];
            float h = acc + bj;
            out[(size_t)n * FDIM + j] = h;
            lsum += h;
            lsq += h * h;
        }
    }
    __syncthreads();
    red[tid] = lsum;
    __syncthreads();
    if (nl == 0) atomicAdd(&ssum[j], red[j] + red[64 + j] + red[128 + j] + red[192 + j]);
    __syncthreads();
    red[tid] = lsq;
    __syncthreads();
    if (nl == 0) atomicAdd(&ssq[j], red[j] + red[64 + j] + red[128 + j] + red[192 + j]);
}

// ---------------- finalize BN params ----------------
__global__ void k_finalize(const float* __restrict__ ssum, const float* __restrict__ ssq,
                           const float* __restrict__ g, float* __restrict__ mu,
                           float* __restrict__ coef, int N) {
    int j = threadIdx.x;
    float m = ssum[j] / (float)N;
    float v = ssq[j] / (float)N - m * m;
    mu[j] = m;
    coef[j] = rsqrtf(v + EPS) * g[j];
}

// ---------------- out = relu((h-mu)*coef+be) * rsqrt(max(degO,1)) ----------------
__global__ void k_bnrelu_scale(const float4* __restrict__ h, const float* __restrict__ mu,
                               const float* __restrict__ coef, const float* __restrict__ be,
                               const int* __restrict__ degO, float4* __restrict__ out, int n4) {
    int i = blockIdx.x * blockDim.x + threadIdx.x;
    if (i < n4) {
        int n = i >> 4;
        int j4 = (i & 15) << 2;
        float rs = rsqrtf((float)max(degO[n], 1));
        float4 v = h[i];
        v.x = fmaxf((v.x - mu[j4 + 0]) * coef[j4 + 0] + be[j4 + 0], 0.f) * rs;
        v.y = fmaxf((v.y - mu[j4 + 1]) * coef[j4 + 1] + be[j4 + 1], 0.f) * rs;
        v.z = fmaxf((v.z - mu[j4 + 2]) * coef[j4 + 2] + be[j4 + 2], 0.f) * rs;
        v.w = fmaxf((v.w - mu[j4 + 3]) * coef[j4 + 3] + be[j4 + 3], 0.f) * rs;
        out[i] = v;
    }
}

// ---------------- relu(bn(h)) channel-sum over nodes ----------------
__global__ void k_bnrelu_mean(const float* __restrict__ h, const float* __restrict__ mu,
                              const float* __restrict__ coef, const float* __restrict__ be,
                              float* __restrict__ hsum, int N) {
    __shared__ float red[256];
    int tid = threadIdx.x;
    int j  = tid & 63;
    int nl = tid >> 6;
    float muj = mu[j], cj = coef[j], bj = be[j];
    float ls = 0.f;
    int nchunks = (N + 3) >> 2;
    for (int chunk = blockIdx.x; chunk < nchunks; chunk += gridDim.x) {
        int n = (chunk << 2) + nl;
        if (n < N) {
            float v = fmaxf((h[(size_t)n * FDIM + j] - muj) * cj + bj, 0.f);
            ls += v;
        }
    }
    red[tid] = ls;
    __syncthreads();
    if (nl == 0) atomicAdd(&hsum[j], red[j] + red[64 + j] + red[128 + j] + red[192 + j]);
}

// ---------------- classifier ----------------
__global__ void k_final(const float* __restrict__ hsum, const float* __restrict__ Wc,
                        const float* __restrict__ bc, float* __restrict__ out, int N) {
    __shared__ float red[128];
    int j = threadIdx.x;
    float hg = hsum[j] / (float)N;
    red[j]      = hg * Wc[j * 2 + 0];
    red[64 + j] = hg * Wc[j * 2 + 1];
    __syncthreads();
    if (j == 0) {
        float a = 0.f, b = 0.f;
        for (int k = 0; k < 64; ++k) { a += red[k]; b += red[64 + k]; }
        out[0] = a + bc[0];
        out[1] = b + bc[1];
    }
}

extern "C" void kernel_launch(void* const* d_in, const int* in_sizes, int n_in,
                              void* d_out, int out_size, void* d_ws, size_t ws_size,
                              hipStream_t stream) {
    const float* x   = (const float*)d_in[0];
    const int*   src = (const int*)d_in[1];
    const int*   dst = (const int*)d_in[2];
    const float* W1  = (const float*)d_in[3];
    const float* b1  = (const float*)d_in[4];
    const float* g1  = (const float*)d_in[5];
    const float* be1 = (const float*)d_in[6];
    const float* W2  = (const float*)d_in[7];
    const float* b2  = (const float*)d_in[8];
    const float* g2  = (const float*)d_in[9];
    const float* be2 = (const float*)d_in[10];
    const float* Wc  = (const float*)d_in[11];
    const float* bc  = (const float*)d_in[12];
    float* out = (float*)d_out;

    const int N = in_sizes[0] / FDIM;   // 100000
    const int E = in_sizes[1];          // 1600000

    // ---- workspace layout ----
    char* w = (char*)d_ws;
    float* bufA    = (float*)w;                                   // N*64 f
    float* bufB    = bufA + (size_t)N * FDIM;                     // N*64 f
    int*   csr_src = (int*)(bufB + (size_t)N * FDIM);             // E int
    int*   degO    = csr_src + E;                                 // N int
    int*   rowptr  = degO + N;                                    // N+2 int
    int*   histS   = rowptr + N + 2;                              // RB*NBUCK int
    int*   histD   = histS + RB * NBUCK;                          // RB*NBUCK int
    int*   baseS   = histD + RB * NBUCK;                          // NBUCK+1
    int*   baseD   = baseS + NBUCK + 1;                           // NBUCK+1
    float* stats   = (float*)(baseD + NBUCK + 1);                 // 1024 f } memset

    // tmp bucket payloads alias the big buffers (dead before bufA/bufB first writes)
    unsigned char* tmpS = (unsigned char*)bufA;                   // E bytes
    int*           tmpD = (int*)bufB;                             // E int

    float* sum1  = stats + 0;
    float* sq1   = stats + 64;
    float* mu1   = stats + 128;
    float* coef1 = stats + 192;
    float* sum2  = stats + 256;
    float* sq2   = stats + 320;
    float* mu2   = stats + 384;
    float* coef2 = stats + 448;
    float* hsum  = stats + 512;

    const int n4 = N * (FDIM / 4);
    const int spmm_blocks = (N * (FDIM / 4) + 63) / 64;   // N waves, 4 waves/block
    const int nbuck_active = (N + LOWMASK) >> LOWB;       // 782 for N=100000
    const int chunk = ((E + RB - 1) / RB + 3) & ~3;       // per-block edges, mult of 4

    hipMemsetAsync(stats, 0, 1024 * 4, stream);

    k_hist<<<RB, RT, 0, stream>>>(src, dst, histS, histD, E, chunk);
    k_scan<<<2, NBUCK, 0, stream>>>(histS, baseS, histD, baseD, RB);
    k_bucket<<<RB, RT, 0, stream>>>(src, dst, histS, histD, tmpS, tmpD, E, chunk);
    k_finebucket<<<nbuck_active, 256, 0, stream>>>(tmpD, baseD, csr_src, rowptr, N);
    k_finehist<<<nbuck_active, 256, 0, stream>>>(tmpS, baseS, degO, N);

    k_scalex<<<(n4 + 255) / 256, 256, 0, stream>>>((const float4*)x, degO, (float4*)bufA, n4);
    k_spmm_csr<<<spmm_blocks, 256, 0, stream>>>(bufA, rowptr, csr_src, bufB, N);
    k_gemm_stats<<<1024, 256, 0, stream>>>(bufB, W1, b1, bufA, sum1, sq1, N);
    k_finalize<<<1, 64, 0, stream>>>(sum1, sq1, g1, mu1, coef1, N);
    k_bnrelu_scale<<<(n4 + 255) / 256, 256, 0, stream>>>((const float4*)bufA, mu1, coef1, be1,
                                                         degO, (float4*)bufB, n4);
    k_spmm_csr<<<spmm_blocks, 256, 0, stream>>>(bufB, rowptr, csr_src, bufA, N);
    k_gemm_stats<<<1024, 256, 0, stream>>>(bufA, W2, b2, bufB, sum2, sq2, N);
    k_finalize<<<1, 64, 0, stream>>>(sum2, sq2, g2, mu2, coef2, N);
    k_bnrelu_mean<<<1024, 256, 0, stream>>>(bufB, mu2, coef2, be2, hsum, N);
    k_final<<<1, 64, 0, stream>>>(hsum, Wc, bc, out, N);
}

// Round 6
// 489.127 us; speedup vs baseline: 2.1015x; 1.0439x over previous
//
#include <hip/hip_runtime.h>

#define FDIM 64
#define EPS 1e-5f
#define NBUCK 1024     // coarse buckets = high bits of 17-bit id
#define LOWB 7
#define LOWMASK 127
#define RB 128         // radix blocks
#define RT 1024        // radix threads per block

// ---------------- per-block coarse histograms of src>>7 and dst>>7 ----------------
__global__ void k_hist(const int* __restrict__ src, const int* __restrict__ dst,
                       int* __restrict__ histS, int* __restrict__ histD, int E, int chunk) {
    __shared__ int hs[NBUCK], hd[NBUCK];
    int tid = threadIdx.x;            // RT == NBUCK == 1024
    hs[tid] = 0; hd[tid] = 0;
    __syncthreads();
    int b = blockIdx.x;
    int beg = b * chunk;
    int end = min(E, beg + chunk);
    int i = beg + tid * 4;
    for (; i + 3 < end; i += RT * 4) {
        int4 s = *(const int4*)(src + i);
        int4 d = *(const int4*)(dst + i);
        atomicAdd(&hs[s.x >> LOWB], 1); atomicAdd(&hd[d.x >> LOWB], 1);
        atomicAdd(&hs[s.y >> LOWB], 1); atomicAdd(&hd[d.y >> LOWB], 1);
        atomicAdd(&hs[s.z >> LOWB], 1); atomicAdd(&hd[d.z >> LOWB], 1);
        atomicAdd(&hs[s.w >> LOWB], 1); atomicAdd(&hd[d.w >> LOWB], 1);
    }
    if (i < end) {
        for (int j = i; j < end && j < i + 4; ++j) {
            atomicAdd(&hs[src[j] >> LOWB], 1);
            atomicAdd(&hd[dst[j] >> LOWB], 1);
        }
    }
    __syncthreads();
    histS[b * NBUCK + tid] = hs[tid];
    histD[b * NBUCK + tid] = hd[tid];
}

// ---------------- scan the [RB][NBUCK] matrix -> per-block offsets + bucket bases ----------------
__global__ void k_scan(int* __restrict__ histS, int* __restrict__ baseS,
                       int* __restrict__ histD, int* __restrict__ baseD, int B) {
    int* hist = (blockIdx.x == 0) ? histS : histD;
    int* base = (blockIdx.x == 0) ? baseS : baseD;
    __shared__ int s[NBUCK];
    int k = threadIdx.x;
    int run = 0;
    for (int b = 0; b < B; ++b) {
        int t = hist[b * NBUCK + k];
        hist[b * NBUCK + k] = run;
        run += t;
    }
    s[k] = run;
    __syncthreads();
    for (int off = 1; off < NBUCK; off <<= 1) {
        int t = (k >= off) ? s[k - off] : 0;
        __syncthreads();
        s[k] += t;
        __syncthreads();
    }
    int excl = (k > 0) ? s[k - 1] : 0;
    base[k] = excl;
    if (k == NBUCK - 1) base[NBUCK] = s[NBUCK - 1];
    for (int b = 0; b < B; ++b)
        hist[b * NBUCK + k] += excl;
}

// ---------------- coarse partition: LDS cursors per block, no global atomics ----------------
__global__ void k_bucket(const int* __restrict__ src, const int* __restrict__ dst,
                         const int* __restrict__ histS, const int* __restrict__ histD,
                         unsigned char* __restrict__ tmpS, int* __restrict__ tmpD,
                         int E, int chunk) {
    __shared__ int curS[NBUCK], curD[NBUCK];
    int tid = threadIdx.x;
    int b = blockIdx.x;
    curS[tid] = histS[b * NBUCK + tid];
    curD[tid] = histD[b * NBUCK + tid];
    __syncthreads();
    int beg = b * chunk;
    int end = min(E, beg + chunk);
    int i = beg + tid * 4;
    for (; i + 3 < end; i += RT * 4) {
        int4 s = *(const int4*)(src + i);
        int4 d = *(const int4*)(dst + i);
        int p;
        p = atomicAdd(&curS[s.x >> LOWB], 1); tmpS[p] = (unsigned char)(s.x & LOWMASK);
        p = atomicAdd(&curS[s.y >> LOWB], 1); tmpS[p] = (unsigned char)(s.y & LOWMASK);
        p = atomicAdd(&curS[s.z >> LOWB], 1); tmpS[p] = (unsigned char)(s.z & LOWMASK);
        p = atomicAdd(&curS[s.w >> LOWB], 1); tmpS[p] = (unsigned char)(s.w & LOWMASK);
        p = atomicAdd(&curD[d.x >> LOWB], 1); tmpD[p] = (s.x << LOWB) | (d.x & LOWMASK);
        p = atomicAdd(&curD[d.y >> LOWB], 1); tmpD[p] = (s.y << LOWB) | (d.y & LOWMASK);
        p = atomicAdd(&curD[d.z >> LOWB], 1); tmpD[p] = (s.z << LOWB) | (d.z & LOWMASK);
        p = atomicAdd(&curD[d.w >> LOWB], 1); tmpD[p] = (s.w << LOWB) | (d.w & LOWMASK);
    }
    if (i < end) {
        for (int j = i; j < end && j < i + 4; ++j) {
            int sv = src[j], dv = dst[j];
            int p = atomicAdd(&curS[sv >> LOWB], 1);
            tmpS[p] = (unsigned char)(sv & LOWMASK);
            p = atomicAdd(&curD[dv >> LOWB], 1);
            tmpD[p] = (sv << LOWB) | (dv & LOWMASK);
        }
    }
}

// ---------------- per-bucket: fine hist + scan -> rowptr, LDS-cursor scatter -> csr_src ----------------
__global__ void k_finebucket(const int* __restrict__ tmp, const int* __restrict__ base,
                             int* __restrict__ csr_src, int* __restrict__ rowptr, int N) {
    __shared__ int hist[128];
    __shared__ int scanv[128];
    int b = blockIdx.x;
    int tid = threadIdx.x;
    int s0 = base[b];
    int s1 = base[b + 1];
    if (tid < 128) hist[tid] = 0;
    __syncthreads();
    for (int i = s0 + tid; i < s1; i += 256)
        atomicAdd(&hist[tmp[i] & LOWMASK], 1);
    __syncthreads();
    int mine = (tid < 128) ? hist[tid] : 0;
    if (tid < 128) scanv[tid] = mine;
    __syncthreads();
    for (int off = 1; off < 128; off <<= 1) {
        int t = (tid < 128 && tid >= off) ? scanv[tid - off] : 0;
        __syncthreads();
        if (tid < 128) scanv[tid] += t;
        __syncthreads();
    }
    if (tid < 128) {
        int excl = scanv[tid] - mine;       // exclusive scan
        int d = (b << LOWB) + tid;
        if (d <= N) rowptr[d] = s0 + excl;  // covers rowptr[N]=E too
        hist[tid] = excl;                   // LDS cursors
    }
    __syncthreads();
    for (int i = s0 + tid; i < s1; i += 256) {
        int p = tmp[i];
        int pos = atomicAdd(&hist[p & LOWMASK], 1);
        csr_src[s0 + pos] = p >> LOWB;
    }
}

// ---------------- per-bucket histogram only -> degO ----------------
__global__ void k_finehist(const unsigned char* __restrict__ tmp, const int* __restrict__ base,
                           int* __restrict__ degO, int N) {
    __shared__ int hist[128];
    int b = blockIdx.x;
    int tid = threadIdx.x;
    int s0 = base[b];
    int s1 = base[b + 1];
    if (tid < 128) hist[tid] = 0;
    __syncthreads();
    for (int i = s0 + tid; i < s1; i += 256)
        atomicAdd(&hist[tmp[i]], 1);
    __syncthreads();
    if (tid < 128) {
        int d = (b << LOWB) + tid;
        if (d < N) degO[d] = hist[tid];
    }
}

// ---------------- bufA = x * rsqrt(max(degO,1)) ----------------
__global__ void k_scalex(const float4* __restrict__ x, const int* __restrict__ degO,
                         float4* __restrict__ out, int n4) {
    int i = blockIdx.x * blockDim.x + threadIdx.x;
    if (i < n4) {
        int n = i >> 4;
        float rs = rsqrtf((float)max(degO[n], 1));
        float4 v = x[i];
        v.x *= rs; v.y *= rs; v.z *= rs; v.w *= rs;
        out[i] = v;
    }
}

// ---------------- CSR SpMM: one wave per dst node, lane = feature ----------------
__global__ void k_spmm_csr(const float* __restrict__ hin, const int* __restrict__ rowptr,
                           const int* __restrict__ csr_src, float* __restrict__ out, int N) {
    int wave = (blockIdx.x * blockDim.x + threadIdx.x) >> 6;
    int lane = threadIdx.x & 63;
    if (wave >= N) return;
    int start = rowptr[wave];
    int end   = rowptr[wave + 1];
    float a0 = 0.f, a1 = 0.f, a2 = 0.f, a3 = 0.f;
    int e = start;
    for (; e + 4 <= end; e += 4) {
        int s0 = csr_src[e];
        int s1 = csr_src[e + 1];
        int s2 = csr_src[e + 2];
        int s3 = csr_src[e + 3];
        a0 += hin[(size_t)s0 * FDIM + lane];
        a1 += hin[(size_t)s1 * FDIM + lane];
        a2 += hin[(size_t)s2 * FDIM + lane];
        a3 += hin[(size_t)s3 * FDIM + lane];
    }
    for (; e < end; ++e)
        a0 += hin[(size_t)csr_src[e] * FDIM + lane];
    float rs = rsqrtf(fmaxf((float)(end - start), 1.0f));
    out[(size_t)wave * FDIM + lane] = ((a0 + a1) + (a2 + a3)) * rs;
}

// ---------------- register GEMM: 1 thread = 1 node; W rows via scalar loads ----------------
// out[n][j] = sum_k m[n][k] * W[k][j] + b[j]
__global__ void k_gemm_reg(const float* __restrict__ m, const float* __restrict__ W,
                           const float* __restrict__ b, float* __restrict__ out, int N) {
    int n = blockIdx.x * blockDim.x + threadIdx.x;
    if (n >= N) return;
    const float* mrow = m + (size_t)n * FDIM;
    float acc[FDIM];
#pragma unroll
    for (int j = 0; j < FDIM; ++j) acc[j] = b[j];        // b[j] wave-uniform -> s_load
    for (int k0 = 0; k0 < FDIM; k0 += 8) {
        float4 ma = *(const float4*)(mrow + k0);
        float4 mb = *(const float4*)(mrow + k0 + 4);
        float mreg[8] = {ma.x, ma.y, ma.z, ma.w, mb.x, mb.y, mb.z, mb.w};
#pragma unroll
        for (int k1 = 0; k1 < 8; ++k1) {
            const float* Wrow = W + (k0 + k1) * FDIM;    // wave-uniform row -> s_load
#pragma unroll
            for (int j = 0; j < FDIM; ++j)
                acc[j] = fmaf(mreg[k1], Wrow[j], acc[j]);
        }
    }
    float4* o = (float4*)(out + (size_t)n * FDIM);
#pragma unroll
    for (int j = 0; j < FDIM; j += 4) {
        float4 v = {acc[j], acc[j + 1], acc[j + 2], acc[j + 3]};
        o[j >> 2] = v;
    }
}

// ---------------- BN stats: per-channel sum and sum-of-squares ----------------
__global__ void k_stats(const float* __restrict__ h, float* __restrict__ ssum,
                        float* __restrict__ ssq, int N) {
    __shared__ float red[256];
    int tid = threadIdx.x;
    int j  = tid & 63;
    int nl = tid >> 6;
    float ls = 0.f, lq = 0.f;
    int stride = gridDim.x * 4;
    for (int n = blockIdx.x * 4 + nl; n < N; n += stride) {
        float v = h[(size_t)n * FDIM + j];
        ls += v;
        lq += v * v;
    }
    red[tid] = ls;
    __syncthreads();
    if (nl == 0) atomicAdd(&ssum[j], red[j] + red[64 + j] + red[128 + j] + red[192 + j]);
    __syncthreads();
    red[tid] = lq;
    __syncthreads();
    if (nl == 0) atomicAdd(&ssq[j], red[j] + red[64 + j] + red[128 + j] + red[192 + j]);
}

// ---------------- finalize BN params ----------------
__global__ void k_finalize(const float* __restrict__ ssum, const float* __restrict__ ssq,
                           const float* __restrict__ g, float* __restrict__ mu,
                           float* __restrict__ coef, int N) {
    int j = threadIdx.x;
    float m = ssum[j] / (float)N;
    float v = ssq[j] / (float)N - m * m;
    mu[j] = m;
    coef[j] = rsqrtf(v + EPS) * g[j];
}

// ---------------- out = relu((h-mu)*coef+be) * rsqrt(max(degO,1)) ----------------
__global__ void k_bnrelu_scale(const float4* __restrict__ h, const float* __restrict__ mu,
                               const float* __restrict__ coef, const float* __restrict__ be,
                               const int* __restrict__ degO, float4* __restrict__ out, int n4) {
    int i = blockIdx.x * blockDim.x + threadIdx.x;
    if (i < n4) {
        int n = i >> 4;
        int j4 = (i & 15) << 2;
        float rs = rsqrtf((float)max(degO[n], 1));
        float4 v = h[i];
        v.x = fmaxf((v.x - mu[j4 + 0]) * coef[j4 + 0] + be[j4 + 0], 0.f) * rs;
        v.y = fmaxf((v.y - mu[j4 + 1]) * coef[j4 + 1] + be[j4 + 1], 0.f) * rs;
        v.z = fmaxf((v.z - mu[j4 + 2]) * coef[j4 + 2] + be[j4 + 2], 0.f) * rs;
        v.w = fmaxf((v.w - mu[j4 + 3]) * coef[j4 + 3] + be[j4 + 3], 0.f) * rs;
        out[i] = v;
    }
}

// ---------------- relu(bn(h)) channel-sum over nodes ----------------
__global__ void k_bnrelu_mean(const float* __restrict__ h, const float* __restrict__ mu,
                              const float* __restrict__ coef, const float* __restrict__ be,
                              float* __restrict__ hsum, int N) {
    __shared__ float red[256];
    int tid = threadIdx.x;
    int j  = tid & 63;
    int nl = tid >> 6;
    float muj = mu[j], cj = coef[j], bj = be[j];
    float ls = 0.f;
    int nchunks = (N + 3) >> 2;
    for (int chunk = blockIdx.x; chunk < nchunks; chunk += gridDim.x) {
        int n = (chunk << 2) + nl;
        if (n < N) {
            float v = fmaxf((h[(size_t)n * FDIM + j] - muj) * cj + bj, 0.f);
            ls += v;
        }
    }
    red[tid] = ls;
    __syncthreads();
    if (nl == 0) atomicAdd(&hsum[j], red[j] + red[64 + j] + red[128 + j] + red[192 + j]);
}

// ---------------- classifier ----------------
__global__ void k_final(const float* __restrict__ hsum, const float* __restrict__ Wc,
                        const float* __restrict__ bc, float* __restrict__ out, int N) {
    __shared__ float red[128];
    int j = threadIdx.x;
    float hg = hsum[j] / (float)N;
    red[j]      = hg * Wc[j * 2 + 0];
    red[64 + j] = hg * Wc[j * 2 + 1];
    __syncthreads();
    if (j == 0) {
        float a = 0.f, b = 0.f;
        for (int k = 0; k < 64; ++k) { a += red[k]; b += red[64 + k]; }
        out[0] = a + bc[0];
        out[1] = b + bc[1];
    }
}

extern "C" void kernel_launch(void* const* d_in, const int* in_sizes, int n_in,
                              void* d_out, int out_size, void* d_ws, size_t ws_size,
                              hipStream_t stream) {
    const float* x   = (const float*)d_in[0];
    const int*   src = (const int*)d_in[1];
    const int*   dst = (const int*)d_in[2];
    const float* W1  = (const float*)d_in[3];
    const float* b1  = (const float*)d_in[4];
    const float* g1  = (const float*)d_in[5];
    const float* be1 = (const float*)d_in[6];
    const float* W2  = (const float*)d_in[7];
    const float* b2  = (const float*)d_in[8];
    const float* g2  = (const float*)d_in[9];
    const float* be2 = (const float*)d_in[10];
    const float* Wc  = (const float*)d_in[11];
    const float* bc  = (const float*)d_in[12];
    float* out = (float*)d_out;

    const int N = in_sizes[0] / FDIM;   // 100000
    const int E = in_sizes[1];          // 1600000

    // ---- workspace layout ----
    char* w = (char*)d_ws;
    float* bufA    = (float*)w;                                   // N*64 f
    float* bufB    = bufA + (size_t)N * FDIM;                     // N*64 f
    int*   csr_src = (int*)(bufB + (size_t)N * FDIM);             // E int
    int*   degO    = csr_src + E;                                 // N int
    int*   rowptr  = degO + N;                                    // N+2 int
    int*   histS   = rowptr + N + 2;                              // RB*NBUCK int
    int*   histD   = histS + RB * NBUCK;                          // RB*NBUCK int
    int*   baseS   = histD + RB * NBUCK;                          // NBUCK+1
    int*   baseD   = baseS + NBUCK + 1;                           // NBUCK+1
    float* stats   = (float*)(baseD + NBUCK + 1);                 // 1024 f } memset

    // tmp bucket payloads alias the big buffers (dead before bufA/bufB first writes)
    unsigned char* tmpS = (unsigned char*)bufA;                   // E bytes
    int*           tmpD = (int*)bufB;                             // E int

    float* sum1  = stats + 0;
    float* sq1   = stats + 64;
    float* mu1   = stats + 128;
    float* coef1 = stats + 192;
    float* sum2  = stats + 256;
    float* sq2   = stats + 320;
    float* mu2   = stats + 384;
    float* coef2 = stats + 448;
    float* hsum  = stats + 512;

    const int n4 = N * (FDIM / 4);
    const int spmm_blocks = (N * (FDIM / 4) + 63) / 64;   // N waves, 4 waves/block
    const int nbuck_active = (N + LOWMASK) >> LOWB;       // 782 for N=100000
    const int chunk = ((E + RB - 1) / RB + 3) & ~3;       // per-block edges, mult of 4

    hipMemsetAsync(stats, 0, 1024 * 4, stream);

    k_hist<<<RB, RT, 0, stream>>>(src, dst, histS, histD, E, chunk);
    k_scan<<<2, NBUCK, 0, stream>>>(histS, baseS, histD, baseD, RB);
    k_bucket<<<RB, RT, 0, stream>>>(src, dst, histS, histD, tmpS, tmpD, E, chunk);
    k_finebucket<<<nbuck_active, 256, 0, stream>>>(tmpD, baseD, csr_src, rowptr, N);
    k_finehist<<<nbuck_active, 256, 0, stream>>>(tmpS, baseS, degO, N);

    k_scalex<<<(n4 + 255) / 256, 256, 0, stream>>>((const float4*)x, degO, (float4*)bufA, n4);
    k_spmm_csr<<<spmm_blocks, 256, 0, stream>>>(bufA, rowptr, csr_src, bufB, N);
    k_gemm_reg<<<(N + 63) / 64, 64, 0, stream>>>(bufB, W1, b1, bufA, N);
    k_stats<<<512, 256, 0, stream>>>(bufA, sum1, sq1, N);
    k_finalize<<<1, 64, 0, stream>>>(sum1, sq1, g1, mu1, coef1, N);
    k_bnrelu_scale<<<(n4 + 255) / 256, 256, 0, stream>>>((const float4*)bufA, mu1, coef1, be1,
                                                         degO, (float4*)bufB, n4);
    k_spmm_csr<<<spmm_blocks, 256, 0, stream>>>(bufB, rowptr, csr_src, bufA, N);
    k_gemm_reg<<<(N + 63) / 64, 64, 0, stream>>>(bufA, W2, b2, bufB, N);
    k_stats<<<512, 256, 0, stream>>>(bufB, sum2, sq2, N);
    k_finalize<<<1, 64, 0, stream>>>(sum2, sq2, g2, mu2, coef2, N);
    k_bnrelu_mean<<<1024, 256, 0, stream>>>(bufB, mu2, coef2, be2, hsum, N);
    k_final<<<1, 64, 0, stream>>>(hsum, Wc, bc, out, N);
}

// Round 7
// 447.873 us; speedup vs baseline: 2.2950x; 1.0921x over previous
//
#include <hip/hip_runtime.h>
#include <hip/hip_fp16.h>

#define FDIM 64
#define EPS 1e-5f
#define NBUCK 1024     // coarse buckets = high bits of 17-bit id
#define LOWB 7
#define LOWMASK 127
#define RB 128         // radix blocks
#define RT 1024        // radix threads per block

// ---------------- per-block coarse histograms of src>>7 and dst>>7 ----------------
__global__ void k_hist(const int* __restrict__ src, const int* __restrict__ dst,
                       int* __restrict__ histS, int* __restrict__ histD, int E, int chunk) {
    __shared__ int hs[NBUCK], hd[NBUCK];
    int tid = threadIdx.x;            // RT == NBUCK == 1024
    hs[tid] = 0; hd[tid] = 0;
    __syncthreads();
    int b = blockIdx.x;
    int beg = b * chunk;
    int end = min(E, beg + chunk);
    int i = beg + tid * 4;
    for (; i + 3 < end; i += RT * 4) {
        int4 s = *(const int4*)(src + i);
        int4 d = *(const int4*)(dst + i);
        atomicAdd(&hs[s.x >> LOWB], 1); atomicAdd(&hd[d.x >> LOWB], 1);
        atomicAdd(&hs[s.y >> LOWB], 1); atomicAdd(&hd[d.y >> LOWB], 1);
        atomicAdd(&hs[s.z >> LOWB], 1); atomicAdd(&hd[d.z >> LOWB], 1);
        atomicAdd(&hs[s.w >> LOWB], 1); atomicAdd(&hd[d.w >> LOWB], 1);
    }
    if (i < end) {
        for (int j = i; j < end && j < i + 4; ++j) {
            atomicAdd(&hs[src[j] >> LOWB], 1);
            atomicAdd(&hd[dst[j] >> LOWB], 1);
        }
    }
    __syncthreads();
    histS[b * NBUCK + tid] = hs[tid];
    histD[b * NBUCK + tid] = hd[tid];
}

// ---------------- scan the [RB][NBUCK] matrix -> per-block offsets + bucket bases ----------------
__global__ void k_scan(int* __restrict__ histS, int* __restrict__ baseS,
                       int* __restrict__ histD, int* __restrict__ baseD, int B) {
    int* hist = (blockIdx.x == 0) ? histS : histD;
    int* base = (blockIdx.x == 0) ? baseS : baseD;
    __shared__ int s[NBUCK];
    int k = threadIdx.x;
    int run = 0;
    for (int b = 0; b < B; b += 4) {     // B % 4 == 0; 4 independent loads per round
        int t0 = hist[(b + 0) * NBUCK + k];
        int t1 = hist[(b + 1) * NBUCK + k];
        int t2 = hist[(b + 2) * NBUCK + k];
        int t3 = hist[(b + 3) * NBUCK + k];
        hist[(b + 0) * NBUCK + k] = run; run += t0;
        hist[(b + 1) * NBUCK + k] = run; run += t1;
        hist[(b + 2) * NBUCK + k] = run; run += t2;
        hist[(b + 3) * NBUCK + k] = run; run += t3;
    }
    s[k] = run;
    __syncthreads();
    for (int off = 1; off < NBUCK; off <<= 1) {
        int t = (k >= off) ? s[k - off] : 0;
        __syncthreads();
        s[k] += t;
        __syncthreads();
    }
    int excl = (k > 0) ? s[k - 1] : 0;
    base[k] = excl;
    if (k == NBUCK - 1) base[NBUCK] = s[NBUCK - 1];
    for (int b = 0; b < B; ++b)
        hist[b * NBUCK + k] += excl;
}

// ---------------- coarse partition: LDS cursors per block, no global atomics ----------------
__global__ void k_bucket(const int* __restrict__ src, const int* __restrict__ dst,
                         const int* __restrict__ histS, const int* __restrict__ histD,
                         unsigned char* __restrict__ tmpS, int* __restrict__ tmpD,
                         int E, int chunk) {
    __shared__ int curS[NBUCK], curD[NBUCK];
    int tid = threadIdx.x;
    int b = blockIdx.x;
    curS[tid] = histS[b * NBUCK + tid];
    curD[tid] = histD[b * NBUCK + tid];
    __syncthreads();
    int beg = b * chunk;
    int end = min(E, beg + chunk);
    int i = beg + tid * 4;
    for (; i + 3 < end; i += RT * 4) {
        int4 s = *(const int4*)(src + i);
        int4 d = *(const int4*)(dst + i);
        int p;
        p = atomicAdd(&curS[s.x >> LOWB], 1); tmpS[p] = (unsigned char)(s.x & LOWMASK);
        p = atomicAdd(&curS[s.y >> LOWB], 1); tmpS[p] = (unsigned char)(s.y & LOWMASK);
        p = atomicAdd(&curS[s.z >> LOWB], 1); tmpS[p] = (unsigned char)(s.z & LOWMASK);
        p = atomicAdd(&curS[s.w >> LOWB], 1); tmpS[p] = (unsigned char)(s.w & LOWMASK);
        p = atomicAdd(&curD[d.x >> LOWB], 1); tmpD[p] = (s.x << LOWB) | (d.x & LOWMASK);
        p = atomicAdd(&curD[d.y >> LOWB], 1); tmpD[p] = (s.y << LOWB) | (d.y & LOWMASK);
        p = atomicAdd(&curD[d.z >> LOWB], 1); tmpD[p] = (s.z << LOWB) | (d.z & LOWMASK);
        p = atomicAdd(&curD[d.w >> LOWB], 1); tmpD[p] = (s.w << LOWB) | (d.w & LOWMASK);
    }
    if (i < end) {
        for (int j = i; j < end && j < i + 4; ++j) {
            int sv = src[j], dv = dst[j];
            int p = atomicAdd(&curS[sv >> LOWB], 1);
            tmpS[p] = (unsigned char)(sv & LOWMASK);
            p = atomicAdd(&curD[dv >> LOWB], 1);
            tmpD[p] = (sv << LOWB) | (dv & LOWMASK);
        }
    }
}

// ---------------- per-bucket: fine hist + scan -> rowptr, LDS-cursor scatter -> csr_src ----------------
__global__ void k_finebucket(const int* __restrict__ tmp, const int* __restrict__ base,
                             int* __restrict__ csr_src, int* __restrict__ rowptr, int N) {
    __shared__ int hist[128];
    __shared__ int scanv[128];
    int b = blockIdx.x;
    int tid = threadIdx.x;
    int s0 = base[b];
    int s1 = base[b + 1];
    if (tid < 128) hist[tid] = 0;
    __syncthreads();
    for (int i = s0 + tid; i < s1; i += 256)
        atomicAdd(&hist[tmp[i] & LOWMASK], 1);
    __syncthreads();
    int mine = (tid < 128) ? hist[tid] : 0;
    if (tid < 128) scanv[tid] = mine;
    __syncthreads();
    for (int off = 1; off < 128; off <<= 1) {
        int t = (tid < 128 && tid >= off) ? scanv[tid - off] : 0;
        __syncthreads();
        if (tid < 128) scanv[tid] += t;
        __syncthreads();
    }
    if (tid < 128) {
        int excl = scanv[tid] - mine;       // exclusive scan
        int d = (b << LOWB) + tid;
        if (d <= N) rowptr[d] = s0 + excl;  // covers rowptr[N]=E too
        hist[tid] = excl;                   // LDS cursors
    }
    __syncthreads();
    for (int i = s0 + tid; i < s1; i += 256) {
        int p = tmp[i];
        int pos = atomicAdd(&hist[p & LOWMASK], 1);
        csr_src[s0 + pos] = p >> LOWB;
    }
}

// ---------------- per-bucket histogram only -> degO ----------------
__global__ void k_finehist(const unsigned char* __restrict__ tmp, const int* __restrict__ base,
                           int* __restrict__ degO, int N) {
    __shared__ int hist[128];
    int b = blockIdx.x;
    int tid = threadIdx.x;
    int s0 = base[b];
    int s1 = base[b + 1];
    if (tid < 128) hist[tid] = 0;
    __syncthreads();
    for (int i = s0 + tid; i < s1; i += 256)
        atomicAdd(&hist[tmp[i]], 1);
    __syncthreads();
    if (tid < 128) {
        int d = (b << LOWB) + tid;
        if (d < N) degO[d] = hist[tid];
    }
}

// ---------------- bufA = half(x * rsqrt(max(degO,1))) ----------------
__global__ void k_scalex(const float4* __restrict__ x, const int* __restrict__ degO,
                         float2* __restrict__ out, int n4) {
    int i = blockIdx.x * blockDim.x + threadIdx.x;
    if (i < n4) {
        int n = i >> 4;
        float rs = rsqrtf((float)max(degO[n], 1));
        float4 v = x[i];
        union { __half2 h[2]; float2 f; } u;
        u.h[0] = __floats2half2_rn(v.x * rs, v.y * rs);
        u.h[1] = __floats2half2_rn(v.z * rs, v.w * rs);
        out[i] = u.f;
    }
}

// ---------------- CSR SpMM: one wave per dst node, lane = feature (fp16 in/out, fp32 acc) ----
__global__ void k_spmm_csr(const __half* __restrict__ hin, const int* __restrict__ rowptr,
                           const int* __restrict__ csr_src, __half* __restrict__ out, int N) {
    int wave = (blockIdx.x * blockDim.x + threadIdx.x) >> 6;
    int lane = threadIdx.x & 63;
    if (wave >= N) return;
    int start = rowptr[wave];
    int end   = rowptr[wave + 1];
    float a0 = 0.f, a1 = 0.f, a2 = 0.f, a3 = 0.f;
    int e = start;
    for (; e + 4 <= end; e += 4) {
        int s0 = csr_src[e];
        int s1 = csr_src[e + 1];
        int s2 = csr_src[e + 2];
        int s3 = csr_src[e + 3];
        a0 += __half2float(hin[(size_t)s0 * FDIM + lane]);
        a1 += __half2float(hin[(size_t)s1 * FDIM + lane]);
        a2 += __half2float(hin[(size_t)s2 * FDIM + lane]);
        a3 += __half2float(hin[(size_t)s3 * FDIM + lane]);
    }
    for (; e < end; ++e)
        a0 += __half2float(hin[(size_t)csr_src[e] * FDIM + lane]);
    float rs = rsqrtf(fmaxf((float)(end - start), 1.0f));
    out[(size_t)wave * FDIM + lane] = __float2half(((a0 + a1) + (a2 + a3)) * rs);
}

// ---------------- register GEMM: 1 thread = 1 node; fp16 m in, fp16 h out, fp32 math ------
__global__ void k_gemm_reg(const __half* __restrict__ m, const float* __restrict__ W,
                           const float* __restrict__ b, __half* __restrict__ out, int N) {
    int n = blockIdx.x * blockDim.x + threadIdx.x;
    if (n >= N) return;
    const __half2* mrow = (const __half2*)(m + (size_t)n * FDIM);
    float acc[FDIM];
#pragma unroll
    for (int j = 0; j < FDIM; ++j) acc[j] = b[j];        // b[j] wave-uniform -> s_load
    for (int k0 = 0; k0 < FDIM; k0 += 8) {
        float2 f0 = __half22float2(mrow[(k0 >> 1) + 0]);
        float2 f1 = __half22float2(mrow[(k0 >> 1) + 1]);
        float2 f2 = __half22float2(mrow[(k0 >> 1) + 2]);
        float2 f3 = __half22float2(mrow[(k0 >> 1) + 3]);
        float mreg[8] = {f0.x, f0.y, f1.x, f1.y, f2.x, f2.y, f3.x, f3.y};
#pragma unroll
        for (int k1 = 0; k1 < 8; ++k1) {
            const float* Wrow = W + (k0 + k1) * FDIM;    // wave-uniform row -> s_load
#pragma unroll
            for (int j = 0; j < FDIM; ++j)
                acc[j] = fmaf(mreg[k1], Wrow[j], acc[j]);
        }
    }
    float4* orow = (float4*)(out + (size_t)n * FDIM);
#pragma unroll
    for (int j = 0; j < FDIM; j += 8) {
        union { __half2 h[4]; float4 f; } u;
        u.h[0] = __floats2half2_rn(acc[j + 0], acc[j + 1]);
        u.h[1] = __floats2half2_rn(acc[j + 2], acc[j + 3]);
        u.h[2] = __floats2half2_rn(acc[j + 4], acc[j + 5]);
        u.h[3] = __floats2half2_rn(acc[j + 6], acc[j + 7]);
        orow[j >> 3] = u.f;
    }
}

// ---------------- BN stats: per-channel sum and sum-of-squares (fp16 in) ----------------
__global__ void k_stats(const __half* __restrict__ h, float* __restrict__ ssum,
                        float* __restrict__ ssq, int N) {
    __shared__ float red[256];
    int tid = threadIdx.x;
    int j  = tid & 63;
    int nl = tid >> 6;
    float ls = 0.f, lq = 0.f;
    int stride = gridDim.x * 4;
    for (int n = blockIdx.x * 4 + nl; n < N; n += stride) {
        float v = __half2float(h[(size_t)n * FDIM + j]);
        ls += v;
        lq += v * v;
    }
    red[tid] = ls;
    __syncthreads();
    if (nl == 0) atomicAdd(&ssum[j], red[j] + red[64 + j] + red[128 + j] + red[192 + j]);
    __syncthreads();
    red[tid] = lq;
    __syncthreads();
    if (nl == 0) atomicAdd(&ssq[j], red[j] + red[64 + j] + red[128 + j] + red[192 + j]);
}

// ---------------- finalize BN params ----------------
__global__ void k_finalize(const float* __restrict__ ssum, const float* __restrict__ ssq,
                           const float* __restrict__ g, float* __restrict__ mu,
                           float* __restrict__ coef, int N) {
    int j = threadIdx.x;
    float m = ssum[j] / (float)N;
    float v = ssq[j] / (float)N - m * m;
    mu[j] = m;
    coef[j] = rsqrtf(v + EPS) * g[j];
}

// ---------------- out = half(relu((h-mu)*coef+be) * rsqrt(max(degO,1))) ----------------
__global__ void k_bnrelu_scale(const float2* __restrict__ h, const float* __restrict__ mu,
                               const float* __restrict__ coef, const float* __restrict__ be,
                               const int* __restrict__ degO, float2* __restrict__ out, int n4) {
    int i = blockIdx.x * blockDim.x + threadIdx.x;
    if (i < n4) {
        int n = i >> 4;
        int j4 = (i & 15) << 2;
        float rs = rsqrtf((float)max(degO[n], 1));
        union { __half2 hh[2]; float2 f; } u;
        u.f = h[i];
        float2 v0 = __half22float2(u.hh[0]);
        float2 v1 = __half22float2(u.hh[1]);
        float r0 = fmaxf((v0.x - mu[j4 + 0]) * coef[j4 + 0] + be[j4 + 0], 0.f) * rs;
        float r1 = fmaxf((v0.y - mu[j4 + 1]) * coef[j4 + 1] + be[j4 + 1], 0.f) * rs;
        float r2 = fmaxf((v1.x - mu[j4 + 2]) * coef[j4 + 2] + be[j4 + 2], 0.f) * rs;
        float r3 = fmaxf((v1.y - mu[j4 + 3]) * coef[j4 + 3] + be[j4 + 3], 0.f) * rs;
        union { __half2 hh[2]; float2 f; } o;
        o.hh[0] = __floats2half2_rn(r0, r1);
        o.hh[1] = __floats2half2_rn(r2, r3);
        out[i] = o.f;
    }
}

// ---------------- relu(bn(h)) channel-sum over nodes (fp16 in) ----------------
__global__ void k_bnrelu_mean(const __half* __restrict__ h, const float* __restrict__ mu,
                              const float* __restrict__ coef, const float* __restrict__ be,
                              float* __restrict__ hsum, int N) {
    __shared__ float red[256];
    int tid = threadIdx.x;
    int j  = tid & 63;
    int nl = tid >> 6;
    float muj = mu[j], cj = coef[j], bj = be[j];
    float ls = 0.f;
    int nchunks = (N + 3) >> 2;
    for (int chunk = blockIdx.x; chunk < nchunks; chunk += gridDim.x) {
        int n = (chunk << 2) + nl;
        if (n < N) {
            float v = fmaxf((__half2float(h[(size_t)n * FDIM + j]) - muj) * cj + bj, 0.f);
            ls += v;
        }
    }
    red[tid] = ls;
    __syncthreads();
    if (nl == 0) atomicAdd(&hsum[j], red[j] + red[64 + j] + red[128 + j] + red[192 + j]);
}

// ---------------- classifier ----------------
__global__ void k_final(const float* __restrict__ hsum, const float* __restrict__ Wc,
                        const float* __restrict__ bc, float* __restrict__ out, int N) {
    __shared__ float red[128];
    int j = threadIdx.x;
    float hg = hsum[j] / (float)N;
    red[j]      = hg * Wc[j * 2 + 0];
    red[64 + j] = hg * Wc[j * 2 + 1];
    __syncthreads();
    if (j == 0) {
        float a = 0.f, b = 0.f;
        for (int k = 0; k < 64; ++k) { a += red[k]; b += red[64 + k]; }
        out[0] = a + bc[0];
        out[1] = b + bc[1];
    }
}

extern "C" void kernel_launch(void* const* d_in, const int* in_sizes, int n_in,
                              void* d_out, int out_size, void* d_ws, size_t ws_size,
                              hipStream_t stream) {
    const float* x   = (const float*)d_in[0];
    const int*   src = (const int*)d_in[1];
    const int*   dst = (const int*)d_in[2];
    const float* W1  = (const float*)d_in[3];
    const float* b1  = (const float*)d_in[4];
    const float* g1  = (const float*)d_in[5];
    const float* be1 = (const float*)d_in[6];
    const float* W2  = (const float*)d_in[7];
    const float* b2  = (const float*)d_in[8];
    const float* g2  = (const float*)d_in[9];
    const float* be2 = (const float*)d_in[10];
    const float* Wc  = (const float*)d_in[11];
    const float* bc  = (const float*)d_in[12];
    float* out = (float*)d_out;

    const int N = in_sizes[0] / FDIM;   // 100000
    const int E = in_sizes[1];          // 1600000

    // ---- workspace layout ----
    char* w = (char*)d_ws;
    __half* bufA   = (__half*)w;                                  // N*64 halfs (12.8 MB)
    __half* bufB   = bufA + (size_t)N * FDIM;                     // N*64 halfs
    int*   csr_src = (int*)(bufB + (size_t)N * FDIM);             // E int
    int*   degO    = csr_src + E;                                 // N int
    int*   rowptr  = degO + N;                                    // N+2 int
    int*   histS   = rowptr + N + 2;                              // RB*NBUCK int
    int*   histD   = histS + RB * NBUCK;                          // RB*NBUCK int
    int*   baseS   = histD + RB * NBUCK;                          // NBUCK+1
    int*   baseD   = baseS + NBUCK + 1;                           // NBUCK+1
    float* stats   = (float*)(baseD + NBUCK + 1);                 // 1024 f } memset

    // tmp bucket payloads alias the big buffers (dead before bufA/bufB first writes)
    unsigned char* tmpS = (unsigned char*)bufA;                   // E bytes  <= 12.8 MB
    int*           tmpD = (int*)bufB;                             // E int (6.4 MB) <= 12.8 MB

    float* sum1  = stats + 0;
    float* sq1   = stats + 64;
    float* mu1   = stats + 128;
    float* coef1 = stats + 192;
    float* sum2  = stats + 256;
    float* sq2   = stats + 320;
    float* mu2   = stats + 384;
    float* coef2 = stats + 448;
    float* hsum  = stats + 512;

    const int n4 = N * (FDIM / 4);
    const int spmm_blocks = (N * (FDIM / 4) + 63) / 64;   // N waves, 4 waves/block
    const int nbuck_active = (N + LOWMASK) >> LOWB;       // 782 for N=100000
    const int chunk = ((E + RB - 1) / RB + 3) & ~3;       // per-block edges, mult of 4

    hipMemsetAsync(stats, 0, 1024 * 4, stream);

    k_hist<<<RB, RT, 0, stream>>>(src, dst, histS, histD, E, chunk);
    k_scan<<<2, NBUCK, 0, stream>>>(histS, baseS, histD, baseD, RB);
    k_bucket<<<RB, RT, 0, stream>>>(src, dst, histS, histD, tmpS, tmpD, E, chunk);
    k_finebucket<<<nbuck_active, 256, 0, stream>>>(tmpD, baseD, csr_src, rowptr, N);
    k_finehist<<<nbuck_active, 256, 0, stream>>>(tmpS, baseS, degO, N);

    k_scalex<<<(n4 + 255) / 256, 256, 0, stream>>>((const float4*)x, degO, (float2*)bufA, n4);
    k_spmm_csr<<<spmm_blocks, 256, 0, stream>>>(bufA, rowptr, csr_src, bufB, N);
    k_gemm_reg<<<(N + 63) / 64, 64, 0, stream>>>(bufB, W1, b1, bufA, N);
    k_stats<<<512, 256, 0, stream>>>(bufA, sum1, sq1, N);
    k_finalize<<<1, 64, 0, stream>>>(sum1, sq1, g1, mu1, coef1, N);
    k_bnrelu_scale<<<(n4 + 255) / 256, 256, 0, stream>>>((const float2*)bufA, mu1, coef1, be1,
                                                         degO, (float2*)bufB, n4);
    k_spmm_csr<<<spmm_blocks, 256, 0, stream>>>(bufB, rowptr, csr_src, bufA, N);
    k_gemm_reg<<<(N + 63) / 64, 64, 0, stream>>>(bufA, W2, b2, bufB, N);
    k_stats<<<512, 256, 0, stream>>>(bufB, sum2, sq2, N);
    k_finalize<<<1, 64, 0, stream>>>(sum2, sq2, g2, mu2, coef2, N);
    k_bnrelu_mean<<<1024, 256, 0, stream>>>(bufB, mu2, coef2, be2, hsum, N);
    k_final<<<1, 64, 0, stream>>>(hsum, Wc, bc, out, N);
}

// Round 8
// 393.542 us; speedup vs baseline: 2.6119x; 1.1381x over previous
//
#include <hip/hip_runtime.h>
#include <hip/hip_fp16.h>

#define FDIM 64
#define EPS 1e-5f
#define NBUCK 1024     // coarse buckets = high bits of 17-bit id
#define LOWB 7
#define LOWMASK 127
#define RB 128         // radix blocks
#define RT 1024        // radix threads per block

// ---------------- per-block coarse histograms of src>>7 and dst>>7 ----------------
__global__ void k_hist(const int* __restrict__ src, const int* __restrict__ dst,
                       int* __restrict__ histS, int* __restrict__ histD, int E, int chunk) {
    __shared__ int hs[NBUCK], hd[NBUCK];
    int tid = threadIdx.x;            // RT == NBUCK == 1024
    hs[tid] = 0; hd[tid] = 0;
    __syncthreads();
    int b = blockIdx.x;
    int beg = b * chunk;
    int end = min(E, beg + chunk);
    int i = beg + tid * 4;
    for (; i + 3 < end; i += RT * 4) {
        int4 s = *(const int4*)(src + i);
        int4 d = *(const int4*)(dst + i);
        atomicAdd(&hs[s.x >> LOWB], 1); atomicAdd(&hd[d.x >> LOWB], 1);
        atomicAdd(&hs[s.y >> LOWB], 1); atomicAdd(&hd[d.y >> LOWB], 1);
        atomicAdd(&hs[s.z >> LOWB], 1); atomicAdd(&hd[d.z >> LOWB], 1);
        atomicAdd(&hs[s.w >> LOWB], 1); atomicAdd(&hd[d.w >> LOWB], 1);
    }
    if (i < end) {
        for (int j = i; j < end && j < i + 4; ++j) {
            atomicAdd(&hs[src[j] >> LOWB], 1);
            atomicAdd(&hd[dst[j] >> LOWB], 1);
        }
    }
    __syncthreads();
    histS[b * NBUCK + tid] = hs[tid];
    histD[b * NBUCK + tid] = hd[tid];
}

// ---------------- scan the [RB][NBUCK] matrix -> per-block offsets + bucket bases ----------------
__global__ void k_scan(int* __restrict__ histS, int* __restrict__ baseS,
                       int* __restrict__ histD, int* __restrict__ baseD, int B) {
    int* hist = (blockIdx.x == 0) ? histS : histD;
    int* base = (blockIdx.x == 0) ? baseS : baseD;
    __shared__ int s[NBUCK];
    int k = threadIdx.x;
    int run = 0;
    for (int b = 0; b < B; b += 4) {     // B % 4 == 0; 4 independent loads per round
        int t0 = hist[(b + 0) * NBUCK + k];
        int t1 = hist[(b + 1) * NBUCK + k];
        int t2 = hist[(b + 2) * NBUCK + k];
        int t3 = hist[(b + 3) * NBUCK + k];
        hist[(b + 0) * NBUCK + k] = run; run += t0;
        hist[(b + 1) * NBUCK + k] = run; run += t1;
        hist[(b + 2) * NBUCK + k] = run; run += t2;
        hist[(b + 3) * NBUCK + k] = run; run += t3;
    }
    s[k] = run;
    __syncthreads();
    for (int off = 1; off < NBUCK; off <<= 1) {
        int t = (k >= off) ? s[k - off] : 0;
        __syncthreads();
        s[k] += t;
        __syncthreads();
    }
    int excl = (k > 0) ? s[k - 1] : 0;
    base[k] = excl;
    if (k == NBUCK - 1) base[NBUCK] = s[NBUCK - 1];
    for (int b = 0; b < B; ++b)
        hist[b * NBUCK + k] += excl;
}

// ---------------- coarse partition: LDS cursors per block, no global atomics ----------------
__global__ void k_bucket(const int* __restrict__ src, const int* __restrict__ dst,
                         const int* __restrict__ histS, const int* __restrict__ histD,
                         unsigned char* __restrict__ tmpS, int* __restrict__ tmpD,
                         int E, int chunk) {
    __shared__ int curS[NBUCK], curD[NBUCK];
    int tid = threadIdx.x;
    int b = blockIdx.x;
    curS[tid] = histS[b * NBUCK + tid];
    curD[tid] = histD[b * NBUCK + tid];
    __syncthreads();
    int beg = b * chunk;
    int end = min(E, beg + chunk);
    int i = beg + tid * 4;
    for (; i + 3 < end; i += RT * 4) {
        int4 s = *(const int4*)(src + i);
        int4 d = *(const int4*)(dst + i);
        int p;
        p = atomicAdd(&curS[s.x >> LOWB], 1); tmpS[p] = (unsigned char)(s.x & LOWMASK);
        p = atomicAdd(&curS[s.y >> LOWB], 1); tmpS[p] = (unsigned char)(s.y & LOWMASK);
        p = atomicAdd(&curS[s.z >> LOWB], 1); tmpS[p] = (unsigned char)(s.z & LOWMASK);
        p = atomicAdd(&curS[s.w >> LOWB], 1); tmpS[p] = (unsigned char)(s.w & LOWMASK);
        p = atomicAdd(&curD[d.x >> LOWB], 1); tmpD[p] = (s.x << LOWB) | (d.x & LOWMASK);
        p = atomicAdd(&curD[d.y >> LOWB], 1); tmpD[p] = (s.y << LOWB) | (d.y & LOWMASK);
        p = atomicAdd(&curD[d.z >> LOWB], 1); tmpD[p] = (s.z << LOWB) | (d.z & LOWMASK);
        p = atomicAdd(&curD[d.w >> LOWB], 1); tmpD[p] = (s.w << LOWB) | (d.w & LOWMASK);
    }
    if (i < end) {
        for (int j = i; j < end && j < i + 4; ++j) {
            int sv = src[j], dv = dst[j];
            int p = atomicAdd(&curS[sv >> LOWB], 1);
            tmpS[p] = (unsigned char)(sv & LOWMASK);
            p = atomicAdd(&curD[dv >> LOWB], 1);
            tmpD[p] = (sv << LOWB) | (dv & LOWMASK);
        }
    }
}

// ---------------- per-bucket: fine hist + scan -> rowptr, LDS-cursor scatter -> csr_src ----------------
__global__ void k_finebucket(const int* __restrict__ tmp, const int* __restrict__ base,
                             int* __restrict__ csr_src, int* __restrict__ rowptr, int N) {
    __shared__ int hist[128];
    __shared__ int scanv[128];
    int b = blockIdx.x;
    int tid = threadIdx.x;
    int s0 = base[b];
    int s1 = base[b + 1];
    if (tid < 128) hist[tid] = 0;
    __syncthreads();
    for (int i = s0 + tid; i < s1; i += 256)
        atomicAdd(&hist[tmp[i] & LOWMASK], 1);
    __syncthreads();
    int mine = (tid < 128) ? hist[tid] : 0;
    if (tid < 128) scanv[tid] = mine;
    __syncthreads();
    for (int off = 1; off < 128; off <<= 1) {
        int t = (tid < 128 && tid >= off) ? scanv[tid - off] : 0;
        __syncthreads();
        if (tid < 128) scanv[tid] += t;
        __syncthreads();
    }
    if (tid < 128) {
        int excl = scanv[tid] - mine;       // exclusive scan
        int d = (b << LOWB) + tid;
        if (d <= N) rowptr[d] = s0 + excl;  // covers rowptr[N]=E too
        hist[tid] = excl;                   // LDS cursors
    }
    __syncthreads();
    for (int i = s0 + tid; i < s1; i += 256) {
        int p = tmp[i];
        int pos = atomicAdd(&hist[p & LOWMASK], 1);
        csr_src[s0 + pos] = p >> LOWB;
    }
}

// ---------------- per-bucket histogram only -> degO ----------------
__global__ void k_finehist(const unsigned char* __restrict__ tmp, const int* __restrict__ base,
                           int* __restrict__ degO, int N) {
    __shared__ int hist[128];
    int b = blockIdx.x;
    int tid = threadIdx.x;
    int s0 = base[b];
    int s1 = base[b + 1];
    if (tid < 128) hist[tid] = 0;
    __syncthreads();
    for (int i = s0 + tid; i < s1; i += 256)
        atomicAdd(&hist[tmp[i]], 1);
    __syncthreads();
    if (tid < 128) {
        int d = (b << LOWB) + tid;
        if (d < N) degO[d] = hist[tid];
    }
}

// ---------------- bufA = half(x * rsqrt(max(degO,1))) ----------------
__global__ void k_scalex(const float4* __restrict__ x, const int* __restrict__ degO,
                         float2* __restrict__ out, int n4) {
    int i = blockIdx.x * blockDim.x + threadIdx.x;
    if (i < n4) {
        int n = i >> 4;
        float rs = rsqrtf((float)max(degO[n], 1));
        float4 v = x[i];
        union { __half2 h[2]; float2 f; } u;
        u.h[0] = __floats2half2_rn(v.x * rs, v.y * rs);
        u.h[1] = __floats2half2_rn(v.z * rs, v.w * rs);
        out[i] = u.f;
    }
}

// ---------------- CSR SpMM: 8 rows per wave, 16B/lane slices, fp32 acc ----------------
// lane = (g, sl): group g (lane>>3) owns row wid*8+g; slice sl (lane&7) covers
// features [sl*8, sl*8+8) as one float4 (8 halfs). Per 8-edge chunk: one coalesced
// idx load + 8 x (shfl broadcast + 1KB wave gather of 8 full rows).
__global__ void k_spmm8(const __half* __restrict__ hin, const int* __restrict__ rowptr,
                        const int* __restrict__ csr_src, __half* __restrict__ out, int N) {
    int wid = (blockIdx.x * blockDim.x + threadIdx.x) >> 6;
    int lane = threadIdx.x & 63;
    int g = lane >> 3;
    int sl = lane & 7;
    int row = wid * 8 + g;
    bool rv = row < N;
    int start = rv ? rowptr[row] : 0;
    int end   = rv ? rowptr[row + 1] : 0;
    int deg = end - start;
    int md = deg;
    md = max(md, __shfl_xor(md, 8));
    md = max(md, __shfl_xor(md, 16));
    md = max(md, __shfl_xor(md, 32));
    float acc[8] = {0.f, 0.f, 0.f, 0.f, 0.f, 0.f, 0.f, 0.f};
    for (int it = 0; it < md; it += 8) {
        int a = start + it + sl;
        int ca = (a < end) ? a : ((deg > 0) ? end - 1 : 0);
        int idxv = csr_src[ca];
#pragma unroll
        for (int j = 0; j < 8; ++j) {
            int bidx = __shfl(idxv, (g << 3) + j);
            if (it + j < deg) {
                const float4* gp = (const float4*)(hin + ((size_t)bidx << 6));
                union { float4 f; __half2 h[4]; } u;
                u.f = gp[sl];
                float2 p0 = __half22float2(u.h[0]);
                float2 p1 = __half22float2(u.h[1]);
                float2 p2 = __half22float2(u.h[2]);
                float2 p3 = __half22float2(u.h[3]);
                acc[0] += p0.x; acc[1] += p0.y;
                acc[2] += p1.x; acc[3] += p1.y;
                acc[4] += p2.x; acc[5] += p2.y;
                acc[6] += p3.x; acc[7] += p3.y;
            }
        }
    }
    if (rv) {
        float rs = rsqrtf(fmaxf((float)deg, 1.0f));
        union { float4 f; __half2 h[4]; } o;
        o.h[0] = __floats2half2_rn(acc[0] * rs, acc[1] * rs);
        o.h[1] = __floats2half2_rn(acc[2] * rs, acc[3] * rs);
        o.h[2] = __floats2half2_rn(acc[4] * rs, acc[5] * rs);
        o.h[3] = __floats2half2_rn(acc[6] * rs, acc[7] * rs);
        ((float4*)(out + ((size_t)row << 6)))[sl] = o.f;
    }
}

// ---------------- register GEMM: 1 thread = 1 node; fp16 m in, fp16 h out, fp32 math ------
__global__ void k_gemm_reg(const __half* __restrict__ m, const float* __restrict__ W,
                           const float* __restrict__ b, __half* __restrict__ out, int N) {
    int n = blockIdx.x * blockDim.x + threadIdx.x;
    if (n >= N) return;
    const __half2* mrow = (const __half2*)(m + (size_t)n * FDIM);
    float acc[FDIM];
#pragma unroll
    for (int j = 0; j < FDIM; ++j) acc[j] = b[j];        // b[j] wave-uniform -> s_load
    for (int k0 = 0; k0 < FDIM; k0 += 8) {
        float2 f0 = __half22float2(mrow[(k0 >> 1) + 0]);
        float2 f1 = __half22float2(mrow[(k0 >> 1) + 1]);
        float2 f2 = __half22float2(mrow[(k0 >> 1) + 2]);
        float2 f3 = __half22float2(mrow[(k0 >> 1) + 3]);
        float mreg[8] = {f0.x, f0.y, f1.x, f1.y, f2.x, f2.y, f3.x, f3.y};
#pragma unroll
        for (int k1 = 0; k1 < 8; ++k1) {
            const float* Wrow = W + (k0 + k1) * FDIM;    // wave-uniform row -> s_load
#pragma unroll
            for (int j = 0; j < FDIM; ++j)
                acc[j] = fmaf(mreg[k1], Wrow[j], acc[j]);
        }
    }
    float4* orow = (float4*)(out + (size_t)n * FDIM);
#pragma unroll
    for (int j = 0; j < FDIM; j += 8) {
        union { __half2 h[4]; float4 f; } u;
        u.h[0] = __floats2half2_rn(acc[j + 0], acc[j + 1]);
        u.h[1] = __floats2half2_rn(acc[j + 2], acc[j + 3]);
        u.h[2] = __floats2half2_rn(acc[j + 4], acc[j + 5]);
        u.h[3] = __floats2half2_rn(acc[j + 6], acc[j + 7]);
        orow[j >> 3] = u.f;
    }
}

// ---------------- BN stats: per-channel sum and sum-of-squares (fp16 in) ----------------
__global__ void k_stats(const __half* __restrict__ h, float* __restrict__ ssum,
                        float* __restrict__ ssq, int N) {
    __shared__ float red[256];
    int tid = threadIdx.x;
    int j  = tid & 63;
    int nl = tid >> 6;
    float ls = 0.f, lq = 0.f;
    int stride = gridDim.x * 4;
    for (int n = blockIdx.x * 4 + nl; n < N; n += stride) {
        float v = __half2float(h[(size_t)n * FDIM + j]);
        ls += v;
        lq += v * v;
    }
    red[tid] = ls;
    __syncthreads();
    if (nl == 0) atomicAdd(&ssum[j], red[j] + red[64 + j] + red[128 + j] + red[192 + j]);
    __syncthreads();
    red[tid] = lq;
    __syncthreads();
    if (nl == 0) atomicAdd(&ssq[j], red[j] + red[64 + j] + red[128 + j] + red[192 + j]);
}

// ---------------- finalize BN params ----------------
__global__ void k_finalize(const float* __restrict__ ssum, const float* __restrict__ ssq,
                           const float* __restrict__ g, float* __restrict__ mu,
                           float* __restrict__ coef, int N) {
    int j = threadIdx.x;
    float m = ssum[j] / (float)N;
    float v = ssq[j] / (float)N - m * m;
    mu[j] = m;
    coef[j] = rsqrtf(v + EPS) * g[j];
}

// ---------------- out = half(relu((h-mu)*coef+be) * rsqrt(max(degO,1))) ----------------
__global__ void k_bnrelu_scale(const float2* __restrict__ h, const float* __restrict__ mu,
                               const float* __restrict__ coef, const float* __restrict__ be,
                               const int* __restrict__ degO, float2* __restrict__ out, int n4) {
    int i = blockIdx.x * blockDim.x + threadIdx.x;
    if (i < n4) {
        int n = i >> 4;
        int j4 = (i & 15) << 2;
        float rs = rsqrtf((float)max(degO[n], 1));
        union { __half2 hh[2]; float2 f; } u;
        u.f = h[i];
        float2 v0 = __half22float2(u.hh[0]);
        float2 v1 = __half22float2(u.hh[1]);
        float r0 = fmaxf((v0.x - mu[j4 + 0]) * coef[j4 + 0] + be[j4 + 0], 0.f) * rs;
        float r1 = fmaxf((v0.y - mu[j4 + 1]) * coef[j4 + 1] + be[j4 + 1], 0.f) * rs;
        float r2 = fmaxf((v1.x - mu[j4 + 2]) * coef[j4 + 2] + be[j4 + 2], 0.f) * rs;
        float r3 = fmaxf((v1.y - mu[j4 + 3]) * coef[j4 + 3] + be[j4 + 3], 0.f) * rs;
        union { __half2 hh[2]; float2 f; } o;
        o.hh[0] = __floats2half2_rn(r0, r1);
        o.hh[1] = __floats2half2_rn(r2, r3);
        out[i] = o.f;
    }
}

// ---------------- relu(bn(h)) channel-sum over nodes (fp16 in) ----------------
__global__ void k_bnrelu_mean(const __half* __restrict__ h, const float* __restrict__ mu,
                              const float* __restrict__ coef, const float* __restrict__ be,
                              float* __restrict__ hsum, int N) {
    __shared__ float red[256];
    int tid = threadIdx.x;
    int j  = tid & 63;
    int nl = tid >> 6;
    float muj = mu[j], cj = coef[j], bj = be[j];
    float ls = 0.f;
    int nchunks = (N + 3) >> 2;
    for (int chunk = blockIdx.x; chunk < nchunks; chunk += gridDim.x) {
        int n = (chunk << 2) + nl;
        if (n < N) {
            float v = fmaxf((__half2float(h[(size_t)n * FDIM + j]) - muj) * cj + bj, 0.f);
            ls += v;
        }
    }
    red[tid] = ls;
    __syncthreads();
    if (nl == 0) atomicAdd(&hsum[j], red[j] + red[64 + j] + red[128 + j] + red[192 + j]);
}

// ---------------- classifier ----------------
__global__ void k_final(const float* __restrict__ hsum, const float* __restrict__ Wc,
                        const float* __restrict__ bc, float* __restrict__ out, int N) {
    __shared__ float red[128];
    int j = threadIdx.x;
    float hg = hsum[j] / (float)N;
    red[j]      = hg * Wc[j * 2 + 0];
    red[64 + j] = hg * Wc[j * 2 + 1];
    __syncthreads();
    if (j == 0) {
        float a = 0.f, b = 0.f;
        for (int k = 0; k < 64; ++k) { a += red[k]; b += red[64 + k]; }
        out[0] = a + bc[0];
        out[1] = b + bc[1];
    }
}

extern "C" void kernel_launch(void* const* d_in, const int* in_sizes, int n_in,
                              void* d_out, int out_size, void* d_ws, size_t ws_size,
                              hipStream_t stream) {
    const float* x   = (const float*)d_in[0];
    const int*   src = (const int*)d_in[1];
    const int*   dst = (const int*)d_in[2];
    const float* W1  = (const float*)d_in[3];
    const float* b1  = (const float*)d_in[4];
    const float* g1  = (const float*)d_in[5];
    const float* be1 = (const float*)d_in[6];
    const float* W2  = (const float*)d_in[7];
    const float* b2  = (const float*)d_in[8];
    const float* g2  = (const float*)d_in[9];
    const float* be2 = (const float*)d_in[10];
    const float* Wc  = (const float*)d_in[11];
    const float* bc  = (const float*)d_in[12];
    float* out = (float*)d_out;

    const int N = in_sizes[0] / FDIM;   // 100000
    const int E = in_sizes[1];          // 1600000

    // ---- workspace layout ----
    char* w = (char*)d_ws;
    __half* bufA   = (__half*)w;                                  // N*64 halfs (12.8 MB)
    __half* bufB   = bufA + (size_t)N * FDIM;                     // N*64 halfs
    int*   csr_src = (int*)(bufB + (size_t)N * FDIM);             // E int
    int*   degO    = csr_src + E;                                 // N int
    int*   rowptr  = degO + N;                                    // N+2 int
    int*   histS   = rowptr + N + 2;                              // RB*NBUCK int
    int*   histD   = histS + RB * NBUCK;                          // RB*NBUCK int
    int*   baseS   = histD + RB * NBUCK;                          // NBUCK+1
    int*   baseD   = baseS + NBUCK + 1;                           // NBUCK+1
    float* stats   = (float*)(baseD + NBUCK + 1);                 // 1024 f } memset

    // tmp bucket payloads alias the big buffers (dead before bufA/bufB first writes)
    unsigned char* tmpS = (unsigned char*)bufA;                   // E bytes  <= 12.8 MB
    int*           tmpD = (int*)bufB;                             // E int (6.4 MB) <= 12.8 MB

    float* sum1  = stats + 0;
    float* sq1   = stats + 64;
    float* mu1   = stats + 128;
    float* coef1 = stats + 192;
    float* sum2  = stats + 256;
    float* sq2   = stats + 320;
    float* mu2   = stats + 384;
    float* coef2 = stats + 448;
    float* hsum  = stats + 512;

    const int n4 = N * (FDIM / 4);
    const int spmm8_blocks = ((N + 7) / 8 + 3) / 4;       // 8 rows/wave, 4 waves/block
    const int nbuck_active = (N + LOWMASK) >> LOWB;       // 782 for N=100000
    const int chunk = ((E + RB - 1) / RB + 3) & ~3;       // per-block edges, mult of 4

    hipMemsetAsync(stats, 0, 1024 * 4, stream);

    k_hist<<<RB, RT, 0, stream>>>(src, dst, histS, histD, E, chunk);
    k_scan<<<2, NBUCK, 0, stream>>>(histS, baseS, histD, baseD, RB);
    k_bucket<<<RB, RT, 0, stream>>>(src, dst, histS, histD, tmpS, tmpD, E, chunk);
    k_finebucket<<<nbuck_active, 256, 0, stream>>>(tmpD, baseD, csr_src, rowptr, N);
    k_finehist<<<nbuck_active, 256, 0, stream>>>(tmpS, baseS, degO, N);

    k_scalex<<<(n4 + 255) / 256, 256, 0, stream>>>((const float4*)x, degO, (float2*)bufA, n4);
    k_spmm8<<<spmm8_blocks, 256, 0, stream>>>(bufA, rowptr, csr_src, bufB, N);
    k_gemm_reg<<<(N + 63) / 64, 64, 0, stream>>>(bufB, W1, b1, bufA, N);
    k_stats<<<512, 256, 0, stream>>>(bufA, sum1, sq1, N);
    k_finalize<<<1, 64, 0, stream>>>(sum1, sq1, g1, mu1, coef1, N);
    k_bnrelu_scale<<<(n4 + 255) / 256, 256, 0, stream>>>((const float2*)bufA, mu1, coef1, be1,
                                                         degO, (float2*)bufB, n4);
    k_spmm8<<<spmm8_blocks, 256, 0, stream>>>(bufB, rowptr, csr_src, bufA, N);
    k_gemm_reg<<<(N + 63) / 64, 64, 0, stream>>>(bufA, W2, b2, bufB, N);
    k_stats<<<512, 256, 0, stream>>>(bufB, sum2, sq2, N);
    k_finalize<<<1, 64, 0, stream>>>(sum2, sq2, g2, mu2, coef2, N);
    k_bnrelu_mean<<<1024, 256, 0, stream>>>(bufB, mu2, coef2, be2, hsum, N);
    k_final<<<1, 64, 0, stream>>>(hsum, Wc, bc, out, N);
}